// Round 7
// baseline (288.240 us; speedup 1.0000x reference)
//
#include <hip/hip_runtime.h>
#include <math.h>

#define T_DIM 8192
#define IN_DIM 1024
#define TRACE 64
#define CTX 16
#define OUT_DIM 1024
#define KMIX 2048

typedef __attribute__((ext_vector_type(8))) short bf16x8;
typedef __attribute__((ext_vector_type(4))) float f32x4;
typedef __attribute__((ext_vector_type(16))) float f32x16;

__device__ __forceinline__ unsigned short f2bf(float f) {
    unsigned int u = __float_as_uint(f);
    u = (u + 0x7FFFu + ((u >> 16) & 1u)) >> 16;
    return (unsigned short)u;
}
__device__ __forceinline__ float bf2f(unsigned short b) {
    return __uint_as_float(((unsigned int)b) << 16);
}

__device__ __forceinline__ void gl2lds16(const void* g, void* l) {
    __builtin_amdgcn_global_load_lds(
        (const __attribute__((address_space(1))) unsigned int*)g,
        (__attribute__((address_space(3))) unsigned int*)l,
        16, 0, 0);
}

// ---------------- ws layout (float offsets) ----------------
// gxT   fp32 [64][8192]      @ 0         (524288 f)
// zinb  bf16 [8192][2048]    @ 8912896   (8388608 f)   k-order: k' = m*32 + 2c + (0 re/1 im)
// xb    bf16 [8192][1024]    @ 17301504  (4194304 f)
// gob   bf16 fragment-major  @ 21495808  (524288 f)    D(n,k)=(n>>5)*32768+(k>>5)*1024+kh*512+h*256+(n&31)*8+(k&7)
// skb   bf16 fragment-major  @ 22020096  (524288 f)    same layout as gob
// mixb  bf16 fragment-major  @ 22544384  (1048576 f)   same layout over the k' axis (65536/grp)
// zg    bf16 [8192][1024]    @ 23592960  (4194304 f)   [pwb/gwb borrow pre-gA]
// sk2   bf16 [8192][1024]    @ 27787264  (4194304 f)
// fstate fp32 [2048]         @ 31981568
// mask  u8   [8192]          @ 31983616  (2048 f)
// mask64 u64 [128]           @ 31985664  (256 f)

// ---------------- C0: fp32 -> bf16 conversions + start-mask normalize + bit-pack -------------
// gob/skb/mixb are written FRAGMENT-MAJOR so gA can load B-operand fragments as perfectly
// coalesced global_load_dwordx4 (lane stride 16B) without LDS staging. mixb composes the
// fragment layout with the re/im-interleaved permutation k' = mm*32 + 2cc + p.
__global__ __launch_bounds__(256) void c0_conv(const float* __restrict__ x,
        const float* __restrict__ gw, const float* __restrict__ sw, const float* __restrict__ mw,
        const float* __restrict__ pw, const float* __restrict__ giw,
        const void* __restrict__ startp,
        unsigned short* __restrict__ xb, unsigned short* __restrict__ gob,
        unsigned short* __restrict__ skb, unsigned short* __restrict__ mixb,
        unsigned short* __restrict__ pwb, unsigned short* __restrict__ gwb,
        unsigned char* __restrict__ mask, unsigned long long* __restrict__ mask64)
{
    if (blockIdx.x == 0) {
        __shared__ int nonbool;
        int tid = threadIdx.x;
        if (tid == 0) nonbool = 0;
        __syncthreads();
        const unsigned int* wv = (const unsigned int*)startp;
        #pragma unroll
        for (int p = 0; p < 8; p++) {
            unsigned int a = wv[tid * 8 + p];
            if (a > 1u) nonbool = 1;
        }
        __syncthreads();
        if (nonbool) {
            const unsigned char* s8 = (const unsigned char*)startp;
            for (int i = tid; i < T_DIM; i += 256) mask[i] = (unsigned char)(s8[i] != 0);
        } else {
            const int* s32 = (const int*)startp;
            for (int i = tid; i < T_DIM; i += 256) mask[i] = (unsigned char)(s32[i] != 0);
        }
        __syncthreads();   // mask bytes visible block-wide; pack 64 bits/thread
        if (tid < 128) {
            unsigned long long wv2 = 0ull;
            int base = tid * 64;
            #pragma unroll 8
            for (int b2 = 0; b2 < 64; b2++)
                wv2 |= ((unsigned long long)(mask[base + b2] & 1)) << b2;
            mask64[tid] = wv2;
        }
    }
    // part A: straight conversions (x, pre_w, gi_w)
    const size_t QX = 2097152, QP = 16384, QI = 16384;
    const size_t totalA = QX + QP + QI;
    for (size_t q = (size_t)blockIdx.x * blockDim.x + threadIdx.x; q < totalA;
         q += (size_t)gridDim.x * blockDim.x) {
        const float* src; unsigned short* dst; size_t i;
        if (q < QX)          { src = x;   dst = xb;  i = q; }
        else if (q < QX+QP)  { src = pw;  dst = pwb; i = q - QX; }
        else                 { src = giw; dst = gwb; i = q - QX - QP; }
        float4 v = *(const float4*)(src + i * 4);
        ushort4 o;
        o.x = f2bf(v.x); o.y = f2bf(v.y); o.z = f2bf(v.z); o.w = f2bf(v.w);
        *(ushort4*)(dst + i * 4) = o;
    }
    // part G: go_w / skip_w -> fragment-major (coalesced float4 reads, 8B ushort4 stores)
    const size_t QG = 262144;    // per matrix, in float4s
    for (size_t q = (size_t)blockIdx.x * blockDim.x + threadIdx.x; q < 2 * QG;
         q += (size_t)gridDim.x * blockDim.x) {
        const float* src = (q < QG) ? gw : sw;
        unsigned short* dst = (q < QG) ? gob : skb;
        size_t i = (q < QG) ? q : q - QG;
        float4 v = *(const float4*)(src + i * 4);
        int flat = (int)(i * 4);
        int n = flat >> 10;
        int k = flat & 1023;           // multiple of 4
        int D = (n >> 5) * 32768 + (k >> 5) * 1024 + ((k >> 4) & 1) * 512
              + ((k >> 3) & 1) * 256 + (n & 31) * 8 + (k & 7);
        ushort4 o;
        o.x = f2bf(v.x); o.y = f2bf(v.y); o.z = f2bf(v.z); o.w = f2bf(v.w);
        *(ushort4*)(dst + D) = o;
    }
    // part M: mix_w -> fragment-major over k' = mm*32 + 2*cc + p  (k = mm*32 + p*16 + cc)
    const size_t QM = 524288;
    for (size_t q = (size_t)blockIdx.x * blockDim.x + threadIdx.x; q < QM;
         q += (size_t)gridDim.x * blockDim.x) {
        float4 v = *(const float4*)(mw + q * 4);
        int flat = (int)(q * 4);
        int n  = flat >> 11;
        int kk = flat & 2047;
        int mm = kk >> 5;
        int w_ = kk & 31;
        int p  = w_ >> 4;
        int cc = w_ & 15;              // multiple of 4
        int w2 = 2 * cc + p;           // k' within the 32-block; elements at w2, w2+2, w2+4, w2+6
        int D = (n >> 5) * 65536 + mm * 1024 + (w2 >> 4) * 512
              + ((w2 >> 3) & 1) * 256 + (n & 31) * 8 + (w2 & 7);
        mixb[D]     = f2bf(v.x);
        mixb[D + 2] = f2bf(v.y);
        mixb[D + 4] = f2bf(v.z);
        mixb[D + 6] = f2bf(v.w);
    }
}

// ---------------- K1: MFMA gated_x, 256 blocks of 32t x 128m, swizzled LDS --------------------
__global__ __launch_bounds__(256) void k1_mfma(const unsigned short* __restrict__ xb,
        const unsigned short* __restrict__ pwb, const unsigned short* __restrict__ gwb,
        const float* __restrict__ pre_b, const float* __restrict__ gi_b,
        float* __restrict__ gxT)
{
    __shared__ __align__(16) unsigned short As[1024];
    __shared__ __align__(16) unsigned short Bs[4096];
    __shared__ float sgE[64][33];

    const int tid = threadIdx.x;
    const int t0 = blockIdx.x * 32;
    const int lane = tid & 63, w = tid >> 6;
    const int quad = lane >> 4, l16 = lane & 15;
    const int r = tid >> 2, s4 = tid & 3;
    const int csw = (s4 - ((r >> 1) & 3)) & 3;

    f32x4 acc[2][2];
    const f32x4 zero4 = {0.f, 0.f, 0.f, 0.f};
    #pragma unroll
    for (int mi = 0; mi < 2; mi++)
        #pragma unroll
        for (int ni = 0; ni < 2; ni++) acc[mi][ni] = zero4;

    const int sfr = (quad + ((l16 >> 1) & 3)) & 3;

    for (int k0 = 0; k0 < IN_DIM; k0 += 32) {
        __syncthreads();
        if (tid < 128) {
            int ra = tid >> 2;
            int ca = ((tid & 3) - ((ra >> 1) & 3)) & 3;
            gl2lds16(xb + (size_t)(t0 + ra) * IN_DIM + k0 + ca * 8, As + tid * 8);
        }
        gl2lds16(pwb + (size_t)r * IN_DIM + k0 + csw * 8, Bs + tid * 8);
        gl2lds16(gwb + (size_t)r * IN_DIM + k0 + csw * 8, Bs + 2048 + tid * 8);
        asm volatile("s_waitcnt vmcnt(0)" ::: "memory");
        __syncthreads();
        bf16x8 af[2], bf[2];
        #pragma unroll
        for (int mi = 0; mi < 2; mi++)
            af[mi] = *(const bf16x8*)&As[(mi * 16 + l16) * 32 + sfr * 8];
        #pragma unroll
        for (int ni = 0; ni < 2; ni++)
            bf[ni] = *(const bf16x8*)&Bs[(w * 32 + ni * 16 + l16) * 32 + sfr * 8];
        #pragma unroll
        for (int mi = 0; mi < 2; mi++)
            #pragma unroll
            for (int ni = 0; ni < 2; ni++)
                acc[mi][ni] = __builtin_amdgcn_mfma_f32_16x16x32_bf16(af[mi], bf[ni], acc[mi][ni], 0, 0, 0);
    }

    if (w >= 2) {
        #pragma unroll
        for (int mi = 0; mi < 2; mi++)
            #pragma unroll
            for (int ni = 0; ni < 2; ni++) {
                int mg = (w - 2) * 32 + ni * 16 + l16;
                float gb = gi_b[mg];
                #pragma unroll
                for (int rr = 0; rr < 4; rr++) {
                    int tl = mi * 16 + quad * 4 + rr;
                    sgE[mg][tl] = 1.f / (1.f + expf(-(acc[mi][ni][rr] + gb)));
                }
            }
    }
    __syncthreads();
    if (w < 2) {
        #pragma unroll
        for (int mi = 0; mi < 2; mi++)
            #pragma unroll
            for (int ni = 0; ni < 2; ni++) {
                int mp = w * 32 + ni * 16 + l16;
                float pb = pre_b[mp];
                float4 o;
                float* po = &o.x;
                #pragma unroll
                for (int rr = 0; rr < 4; rr++) {
                    int tl = mi * 16 + quad * 4 + rr;
                    po[rr] = (acc[mi][ni][rr] + pb) * sgE[mp][tl];
                }
                *(float4*)&gxT[(size_t)mp * T_DIM + t0 + mi * 16 + quad * 4] = o;
            }
    }
}

// ---------------- K2: resettable complex scan, FULL-CHIP, direct zinb[t][k'] output -----------
__global__ __launch_bounds__(1024, 1) void k2_scan(const float* __restrict__ gxT,
        const unsigned long long* __restrict__ mask64,
        const float* __restrict__ state_re, const float* __restrict__ state_im,
        const float* __restrict__ ffa_a, const float* __restrict__ ffa_b,
        unsigned short* __restrict__ zinb, float* __restrict__ fstate)
{
    const int m  = blockIdx.x >> 2;
    const int qd = blockIdx.x & 3;             // quarter: t in [qd*2048, qd*2048+2048)
    const int tid = threadIdx.x;
    const int c = tid & 15, j = tid >> 4;      // j in [0,64): pass-1 chunk of 128 t
    __shared__ __align__(16) float gxs[8192 + 128];   // padded: idx = t + (t>>6)
    __shared__ float Br[16][65], Bi[16][65], Er[16][65], Ei[16][65];
    __shared__ unsigned char Rf[16][65];
    __shared__ float B32r[16][16][3], B32i[16][16][3];   // from-zero states after 32/64/96 t
    __shared__ unsigned char sRf[16][16][3];             // reset-in-prefix flags

    const float am = -fabsf(ffa_a[m]);
    const float bc = ffa_b[c];
    const float er = expf(am);
    const float gr = er * cosf(bc);
    const float gi = er * sinf(bc);

    {
        const float4* gx4 = (const float4*)(gxT + (size_t)m * T_DIM);
        #pragma unroll
        for (int it = 0; it < 2; it++) {
            int g = it * 1024 + tid;
            float4 v = gx4[g];
            int t = g * 4;
            gxs[t     + ( t      >> 6)] = v.x;
            gxs[t + 1 + ((t + 1) >> 6)] = v.y;
            gxs[t + 2 + ((t + 2) >> 6)] = v.z;
            gxs[t + 3 + ((t + 3) >> 6)] = v.w;
        }
    }
    const unsigned long long mw0 = mask64[j * 2];
    const unsigned long long mw1 = mask64[j * 2 + 1];
    __syncthreads();

    const int lb = j * 130;
    const int gloc = j - qd * 16;
    const bool own = (unsigned)gloc < 16u;

    float sre = 0.f, sim = 0.f;
    #pragma unroll 8
    for (int i = 0; i < 32; i++) {
        if ((mw0 >> i) & 1ull) { sre = 0.f; sim = 0.f; }
        else { float tr_ = sre * gr - sim * gi; sim = sre * gi + sim * gr; sre = tr_; }
        sre += gxs[lb + i];
    }
    if (own) { B32r[c][gloc][0] = sre; B32i[c][gloc][0] = sim;
               sRf[c][gloc][0] = ((mw0 & 0xffffffffull) != 0ull) ? 1 : 0; }
    #pragma unroll 8
    for (int i = 0; i < 32; i++) {
        if ((mw0 >> (i + 32)) & 1ull) { sre = 0.f; sim = 0.f; }
        else { float tr_ = sre * gr - sim * gi; sim = sre * gi + sim * gr; sre = tr_; }
        sre += gxs[lb + 32 + i];
    }
    if (own) { B32r[c][gloc][1] = sre; B32i[c][gloc][1] = sim;
               sRf[c][gloc][1] = (mw0 != 0ull) ? 1 : 0; }
    #pragma unroll 8
    for (int i = 0; i < 32; i++) {
        if ((mw1 >> i) & 1ull) { sre = 0.f; sim = 0.f; }
        else { float tr_ = sre * gr - sim * gi; sim = sre * gi + sim * gr; sre = tr_; }
        sre += gxs[lb + 65 + i];
    }
    if (own) { B32r[c][gloc][2] = sre; B32i[c][gloc][2] = sim;
               sRf[c][gloc][2] = ((mw0 != 0ull) || ((mw1 & 0xffffffffull) != 0ull)) ? 1 : 0; }
    #pragma unroll 8
    for (int i = 0; i < 32; i++) {
        if ((mw1 >> (i + 32)) & 1ull) { sre = 0.f; sim = 0.f; }
        else { float tr_ = sre * gr - sim * gi; sim = sre * gi + sim * gr; sre = tr_; }
        sre += gxs[lb + 97 + i];
    }
    Br[c][j] = sre; Bi[c][j] = sim; Rf[c][j] = ((mw0 | mw1) != 0ull) ? 1 : 0;
    __syncthreads();

    if (tid < 16) {
        const int cc = tid;
        float b2 = 128.f * ffa_b[cc];
        float e128 = expf(128.f * am);
        float gRr = e128 * cosf(b2);
        float gRi = e128 * sinf(b2);
        float pr = state_re[m * CTX + cc], pi = state_im[m * CTX + cc];
        for (int q2 = 0; q2 < 64; q2++) {
            Er[cc][q2] = pr; Ei[cc][q2] = pi;
            if (Rf[cc][q2]) { pr = Br[cc][q2]; pi = Bi[cc][q2]; }
            else {
                float nr = pr * gRr - pi * gRi + Br[cc][q2];
                pi       = pr * gRi + pi * gRr + Bi[cc][q2];
                pr = nr;
            }
        }
    }
    __syncthreads();

    {
        const int gl2 = j >> 2, s = j & 3;
        const int g = qd * 16 + gl2;
        const unsigned long long w0 = mask64[g * 2];
        const unsigned long long w1 = mask64[g * 2 + 1];
        const unsigned int mbits = (unsigned int)(((s < 2) ? w0 : w1) >> ((s & 1) * 32));
        float str, sti;
        {
            float E_r = Er[c][g], E_i = Ei[c][g];
            if (s == 0) { str = E_r; sti = E_i; }
            else if (sRf[c][gl2][s - 1]) { str = B32r[c][gl2][s - 1]; sti = B32i[c][gl2][s - 1]; }
            else {
                float ang = 32.f * (float)s * bc;
                float mag = expf(32.f * (float)s * am);
                float gsr = mag * cosf(ang), gsi = mag * sinf(ang);
                str = B32r[c][gl2][s - 1] + E_r * gsr - E_i * gsi;
                sti = B32i[c][gl2][s - 1] + E_r * gsi + E_i * gsr;
            }
        }
        const int pb = g * 130 + (s >> 1) * 65 + (s & 1) * 32;
        const int tstart = g * 128 + s * 32;
        unsigned int* zout = (unsigned int*)zinb;
        const int obase = m * CTX + c;
        #pragma unroll 8
        for (int i = 0; i < 32; i++) {
            if ((mbits >> i) & 1u) { str = 0.f; sti = 0.f; }
            else { float tr_ = str * gr - sti * gi; sti = str * gi + sti * gr; str = tr_; }
            str += gxs[pb + i];
            unsigned int u = (unsigned int)f2bf(str) | ((unsigned int)f2bf(sti) << 16);
            zout[((size_t)(tstart + i) << 10) + obase] = u;
        }
        if (qd == 3 && j == 63) {
            fstate[obase]        = str;
            fstate[1024 + obase] = sti;
        }
    }
}

// ---------------- GA: 256x128 tile, 8 waves, BK=32; A via LDS triple-buffer, B/C direct -------
// Round-7: B/C operands (gob/skb/mixb, fragment-major) load global->registers as coalesced
// dwordx4 (L2-hot, reused 4x per XCD), one tile ahead, single register set (WAR-safe: loads
// issue after the MFMA cluster that consumed the previous tile). LDS holds only A (48KB,
// 3 buffers); ds_reads drop 12->4 (fused) and 8->4 (mix) per K-tile; staging 2 loads/thread.
__global__ __launch_bounds__(512, 2) void gA_gemm(
        const unsigned short* __restrict__ xb,   const unsigned short* __restrict__ zinb,
        const unsigned short* __restrict__ gob,  const unsigned short* __restrict__ skb,
        const unsigned short* __restrict__ mixb,
        const float* __restrict__ go_b, const float* __restrict__ skip_b, const float* __restrict__ mix_b,
        unsigned short* __restrict__ zg, unsigned short* __restrict__ sk2)
{
    __shared__ __align__(16) unsigned short L[24576];   // 3 x A-tile (256x32 bf16 = 16KB)
    const int tid = threadIdx.x;
    const int b = blockIdx.x;
    const int xcd = b & 7, q = b >> 3;
    const int t0 = (xcd * 4 + (q >> 3)) * 256;
    const int n0 = (q & 7) * 128;

    const int lane = tid & 63, w = tid >> 6;
    const int wm = w >> 1, wn = w & 1;
    const int l31 = lane & 31, h = lane >> 5;
    const int r = tid >> 2;
    const int csw = ((tid & 3) - ((r >> 1) & 3)) & 3;
    const int c8 = csw * 8;
    const int srot = (l31 >> 1) & 3;
    const int dst8 = tid * 8;

    f32x16 accg[2][2], acck[2][2];
    #pragma unroll
    for (int mi = 0; mi < 2; mi++)
        #pragma unroll
        for (int ni = 0; ni < 2; ni++)
            #pragma unroll
            for (int e = 0; e < 16; e++) { accg[mi][ni][e] = 0.f; acck[mi][ni][e] = 0.f; }

    bf16x8 bgR[2][2], bkR[2][2];   // [ni][kh], single set, loaded one tile ahead

    const unsigned short* bgB[2];
    const unsigned short* bkB[2];
    #pragma unroll
    for (int ni = 0; ni < 2; ni++) {
        int grp = (n0 >> 5) + wn * 2 + ni;
        bgB[ni] = gob + (size_t)grp * 32768 + lane * 8;
        bkB[ni] = skb + (size_t)grp * 32768 + lane * 8;
    }

    const unsigned short* gA0 = xb + (size_t)(t0 + r)       * IN_DIM + c8;
    const unsigned short* gA1 = xb + (size_t)(t0 + 128 + r) * IN_DIM + c8;

#define STAGE_A(bufi, kof, P0, P1) do {                       \
        unsigned short* _b = &L[(bufi) * 8192];               \
        gl2lds16(P0 + (kof), _b + dst8);                      \
        gl2lds16(P1 + (kof), _b + 4096 + dst8);               \
    } while (0)

#define BLOAD_F(T) do {                                       \
        _Pragma("unroll")                                     \
        for (int ni = 0; ni < 2; ni++)                        \
            _Pragma("unroll")                                 \
            for (int kh = 0; kh < 2; kh++) {                  \
                bgR[ni][kh] = *(const bf16x8*)(bgB[ni] + (T) * 1024 + kh * 512); \
                bkR[ni][kh] = *(const bf16x8*)(bkB[ni] + (T) * 1024 + kh * 512); \
            }                                                 \
    } while (0)

#define STEP_F(T, CUR, NXT, DOST, DOB, VMC) do {              \
        const unsigned short* As = &L[(CUR) * 8192];          \
        bf16x8 af[2][2];                                      \
        _Pragma("unroll")                                     \
        for (int mi = 0; mi < 2; mi++)                        \
            _Pragma("unroll")                                 \
            for (int kh = 0; kh < 2; kh++)                    \
                af[mi][kh] = *(const bf16x8*)&As[(wm * 64 + mi * 32 + l31) * 32 + ((kh * 2 + h + srot) & 3) * 8]; \
        if (DOST) STAGE_A(NXT, ((T) + 2) * 32, gA0, gA1);     \
        __builtin_amdgcn_s_setprio(1);                        \
        _Pragma("unroll")                                     \
        for (int mi = 0; mi < 2; mi++)                        \
            _Pragma("unroll")                                 \
            for (int ni = 0; ni < 2; ni++) {                  \
                accg[mi][ni] = __builtin_amdgcn_mfma_f32_32x32x16_bf16(af[mi][0], bgR[ni][0], accg[mi][ni], 0, 0, 0); \
                acck[mi][ni] = __builtin_amdgcn_mfma_f32_32x32x16_bf16(af[mi][0], bkR[ni][0], acck[mi][ni], 0, 0, 0); \
                accg[mi][ni] = __builtin_amdgcn_mfma_f32_32x32x16_bf16(af[mi][1], bgR[ni][1], accg[mi][ni], 0, 0, 0); \
                acck[mi][ni] = __builtin_amdgcn_mfma_f32_32x32x16_bf16(af[mi][1], bkR[ni][1], acck[mi][ni], 0, 0, 0); \
            }                                                 \
        __builtin_amdgcn_s_setprio(0);                        \
        if (DOB) BLOAD_F((T) + 1);                            \
        asm volatile("s_waitcnt vmcnt(" #VMC ")" ::: "memory"); \
        __builtin_amdgcn_s_barrier();                         \
    } while (0)

    // ---- fused phase: go + skip (shared A = xb), K = 1024, 32 tiles of BK=32 ----
    STAGE_A(0, 0, gA0, gA1);
    STAGE_A(1, 32, gA0, gA1);
    BLOAD_F(0);
    asm volatile("s_waitcnt vmcnt(10)" ::: "memory");
    __builtin_amdgcn_s_barrier();

    for (int t3i = 0; t3i < 30; t3i += 3) {
        STEP_F(t3i,     0, 2, 1, 1, 10);
        STEP_F(t3i + 1, 1, 0, 1, 1, 10);
        STEP_F(t3i + 2, 2, 1, 1, 1, 10);
    }
    STEP_F(30, 0, 2, 0, 1, 8);
    STEP_F(31, 1, 0, 0, 0, 0);
#undef STEP_F
#undef BLOAD_F

    // sigmoid (packed bf16 pairs) + sk2 write
    unsigned int sigp[32];
    #pragma unroll
    for (int mi = 0; mi < 2; mi++)
        #pragma unroll
        for (int ni = 0; ni < 2; ni++) {
            int n = n0 + wn * 64 + ni * 32 + l31;
            float gb = go_b[n];
            float sb_ = skip_b[n];
            #pragma unroll
            for (int reg = 0; reg < 16; reg++) {
                int row = (reg & 3) + 8 * (reg >> 2) + 4 * h;
                int t = t0 + wm * 64 + mi * 32 + row;
                float s = 1.f / (1.f + expf(-(accg[mi][ni][reg] + gb)));
                sk2[(size_t)t * OUT_DIM + n] = f2bf((acck[mi][ni][reg] + sb_) * (1.f - s));
                unsigned int pk = (unsigned int)f2bf(s);
                int idx = (mi * 2 + ni) * 8 + (reg >> 1);
                if (reg & 1) sigp[idx] |= pk << 16;
                else         sigp[idx]  = pk;
            }
        }

    // ---- mix phase, K = 2048, 64 tiles of BK=32 ----
    #pragma unroll
    for (int mi = 0; mi < 2; mi++)
        #pragma unroll
        for (int ni = 0; ni < 2; ni++)
            #pragma unroll
            for (int e = 0; e < 16; e++) accg[mi][ni][e] = 0.f;

    const unsigned short* mA0 = zinb + (size_t)(t0 + r)       * KMIX + c8;
    const unsigned short* mA1 = zinb + (size_t)(t0 + 128 + r) * KMIX + c8;
    const unsigned short* bfB[2];
    #pragma unroll
    for (int ni = 0; ni < 2; ni++) {
        int grp = (n0 >> 5) + wn * 2 + ni;
        bfB[ni] = mixb + (size_t)grp * 65536 + lane * 8;
    }

#define BLOAD_M(T) do {                                       \
        _Pragma("unroll")                                     \
        for (int ni = 0; ni < 2; ni++)                        \
            _Pragma("unroll")                                 \
            for (int kh = 0; kh < 2; kh++)                    \
                bgR[ni][kh] = *(const bf16x8*)(bfB[ni] + (T) * 1024 + kh * 512); \
    } while (0)

#define STEP_M(T, CUR, NXT, DOST, DOB, VMC) do {              \
        const unsigned short* As = &L[(CUR) * 8192];          \
        bf16x8 af[2][2];                                      \
        _Pragma("unroll")                                     \
        for (int mi = 0; mi < 2; mi++)                        \
            _Pragma("unroll")                                 \
            for (int kh = 0; kh < 2; kh++)                    \
                af[mi][kh] = *(const bf16x8*)&As[(wm * 64 + mi * 32 + l31) * 32 + ((kh * 2 + h + srot) & 3) * 8]; \
        if (DOST) STAGE_A(NXT, ((T) + 2) * 32, mA0, mA1);     \
        __builtin_amdgcn_s_setprio(1);                        \
        _Pragma("unroll")                                     \
        for (int mi = 0; mi < 2; mi++)                        \
            _Pragma("unroll")                                 \
            for (int ni = 0; ni < 2; ni++) {                  \
                accg[mi][ni] = __builtin_amdgcn_mfma_f32_32x32x16_bf16(af[mi][0], bgR[ni][0], accg[mi][ni], 0, 0, 0); \
                accg[mi][ni] = __builtin_amdgcn_mfma_f32_32x32x16_bf16(af[mi][1], bgR[ni][1], accg[mi][ni], 0, 0, 0); \
            }                                                 \
        __builtin_amdgcn_s_setprio(0);                        \
        if (DOB) BLOAD_M((T) + 1);                            \
        asm volatile("s_waitcnt vmcnt(" #VMC ")" ::: "memory"); \
        __builtin_amdgcn_s_barrier();                         \
    } while (0)

    STAGE_A(0, 0, mA0, mA1);
    STAGE_A(1, 32, mA0, mA1);
    BLOAD_M(0);
    asm volatile("s_waitcnt vmcnt(6)" ::: "memory");
    __builtin_amdgcn_s_barrier();

    for (int t3i = 0; t3i < 60; t3i += 3) {
        STEP_M(t3i,     0, 2, 1, 1, 6);
        STEP_M(t3i + 1, 1, 0, 1, 1, 6);
        STEP_M(t3i + 2, 2, 1, 1, 1, 6);
    }
    STEP_M(60, 0, 2, 1, 1, 6);
    STEP_M(61, 1, 0, 1, 1, 6);
    STEP_M(62, 2, 1, 0, 1, 4);
    STEP_M(63, 0, 2, 0, 0, 0);
#undef STEP_M
#undef BLOAD_M
#undef STAGE_A

    #pragma unroll
    for (int mi = 0; mi < 2; mi++)
        #pragma unroll
        for (int ni = 0; ni < 2; ni++) {
            int n = n0 + wn * 64 + ni * 32 + l31;
            float mb_ = mix_b[n];
            #pragma unroll
            for (int reg = 0; reg < 16; reg++) {
                int row = (reg & 3) + 8 * (reg >> 2) + 4 * h;
                int t = t0 + wm * 64 + mi * 32 + row;
                unsigned int u = sigp[(mi * 2 + ni) * 8 + (reg >> 1)];
                float sig = bf2f((unsigned short)((reg & 1) ? (u >> 16) : (u & 0xffff)));
                zg[(size_t)t * OUT_DIM + n] = f2bf((accg[mi][ni][reg] + mb_) * sig);
            }
        }
}

// ---------------- G3: LayerNorm + residual (bf16 in, fp32 out) + final_state copy ------------
__global__ __launch_bounds__(256) void g3_ln(const unsigned short* __restrict__ zg,
        const unsigned short* __restrict__ sk2, const float* __restrict__ fstate,
        float* __restrict__ out, int out_size)
{
    __shared__ float sb[4], qb[4];
    __shared__ float mu_s, rstd_s;
    const int t = blockIdx.x;
    const int tid = threadIdx.x;
    ushort4 zu = *(const ushort4*)&zg [(size_t)t * OUT_DIM + tid * 4];
    ushort4 su = *(const ushort4*)&sk2[(size_t)t * OUT_DIM + tid * 4];
    float z0 = bf2f(zu.x), z1 = bf2f(zu.y), z2 = bf2f(zu.z), z3 = bf2f(zu.w);
    float s0 = bf2f(su.x), s1 = bf2f(su.y), s2 = bf2f(su.z), s3 = bf2f(su.w);
    float s = z0 + z1 + z2 + z3;
    float q = z0*z0 + z1*z1 + z2*z2 + z3*z3;
    #pragma unroll
    for (int off = 32; off > 0; off >>= 1) {
        s += __shfl_down(s, off, 64);
        q += __shfl_down(q, off, 64);
    }
    int wid = tid >> 6;
    if ((tid & 63) == 0) { sb[wid] = s; qb[wid] = q; }
    __syncthreads();
    if (tid == 0) {
        float S = sb[0] + sb[1] + sb[2] + sb[3];
        float Q = qb[0] + qb[1] + qb[2] + qb[3];
        float mu = S * (1.f / 1024.f);
        float var = Q * (1.f / 1024.f) - mu * mu;
        mu_s = mu; rstd_s = rsqrtf(var + 1e-5f);
    }
    __syncthreads();
    float mu = mu_s, rs = rstd_s;
    float4 o;
    o.x = (z0 - mu) * rs + s0;
    o.y = (z1 - mu) * rs + s1;
    o.z = (z2 - mu) * rs + s2;
    o.w = (z3 - mu) * rs + s3;
    *(float4*)&out[(size_t)t * OUT_DIM + tid * 4] = o;

    if (t < 8) {   // folded g4: final_state copy
        int i = t * 256 + tid;
        long long base = (long long)T_DIM * OUT_DIM;
        if (base + i < (long long)out_size) out[base + i] = fstate[i];
    }
}

extern "C" void kernel_launch(void* const* d_in, const int* in_sizes, int n_in,
                              void* d_out, int out_size, void* d_ws, size_t ws_size,
                              hipStream_t stream) {
    const float* x        = (const float*)d_in[0];
    const float* state_re = (const float*)d_in[1];
    const float* state_im = (const float*)d_in[2];
    const void*  startp   = d_in[3];
    const float* pre_w    = (const float*)d_in[5];
    const float* pre_b    = (const float*)d_in[6];
    const float* gi_w     = (const float*)d_in[7];
    const float* gi_b     = (const float*)d_in[8];
    const float* go_w     = (const float*)d_in[9];
    const float* go_b     = (const float*)d_in[10];
    const float* skip_w   = (const float*)d_in[11];
    const float* skip_b   = (const float*)d_in[12];
    const float* mix_w    = (const float*)d_in[13];
    const float* mix_b    = (const float*)d_in[14];
    const float* ffa_a    = (const float*)d_in[15];
    const float* ffa_b    = (const float*)d_in[16];

    float* ws = (float*)d_ws;
    float*          gxT    = ws;
    unsigned short* zinb   = (unsigned short*)(ws + 8912896);
    unsigned short* xb     = (unsigned short*)(ws + 17301504);
    unsigned short* gob    = (unsigned short*)(ws + 21495808);
    unsigned short* skb    = (unsigned short*)(ws + 22020096);
    unsigned short* mixb   = (unsigned short*)(ws + 22544384);
    unsigned short* zg     = (unsigned short*)(ws + 23592960);
    unsigned short* sk2    = (unsigned short*)(ws + 27787264);
    float*          fstate = ws + 31981568;
    unsigned char*  mask   = (unsigned char*)(ws + 31983616);
    unsigned long long* mask64 = (unsigned long long*)(ws + 31985664);
    unsigned short* pwb    = zg;            // borrow zg region pre-gA
    unsigned short* gwb    = zg + 65536;
    float* out = (float*)d_out;

    hipLaunchKernelGGL(c0_conv,  dim3(1536), dim3(256),  0, stream, x, go_w, skip_w, mix_w, pre_w, gi_w,
                                                          startp, xb, gob, skb, mixb, pwb, gwb, mask, mask64);
    hipLaunchKernelGGL(k1_mfma,  dim3(256),  dim3(256),  0, stream, xb, pwb, gwb, pre_b, gi_b, gxT);
    hipLaunchKernelGGL(k2_scan,  dim3(256),  dim3(1024), 0, stream, gxT, mask64, state_re, state_im, ffa_a, ffa_b, zinb, fstate);
    hipLaunchKernelGGL(gA_gemm,  dim3(256),  dim3(512),  0, stream, xb, zinb, gob, skb, mixb, go_b, skip_b, mix_b, zg, sk2);
    hipLaunchKernelGGL(g3_ln,    dim3(8192), dim3(256),  0, stream, zg, sk2, fstate, out, out_size);
}

// Round 8
// 263.055 us; speedup vs baseline: 1.0957x; 1.0957x over previous
//
#include <hip/hip_runtime.h>
#include <math.h>

#define T_DIM 8192
#define IN_DIM 1024
#define TRACE 64
#define CTX 16
#define OUT_DIM 1024
#define KMIX 2048

typedef __attribute__((ext_vector_type(8))) short bf16x8;
typedef __attribute__((ext_vector_type(4))) float f32x4;
typedef __attribute__((ext_vector_type(16))) float f32x16;

__device__ __forceinline__ unsigned short f2bf(float f) {
    unsigned int u = __float_as_uint(f);
    u = (u + 0x7FFFu + ((u >> 16) & 1u)) >> 16;
    return (unsigned short)u;
}
__device__ __forceinline__ float bf2f(unsigned short b) {
    return __uint_as_float(((unsigned int)b) << 16);
}

__device__ __forceinline__ void gl2lds16(const void* g, void* l) {
    __builtin_amdgcn_global_load_lds(
        (const __attribute__((address_space(1))) unsigned int*)g,
        (__attribute__((address_space(3))) unsigned int*)l,
        16, 0, 0);
}

// ---------------- ws layout (float offsets) ----------------
// gxT   fp32 [64][8192]      @ 0         (524288 f)
// zinb  bf16 [8192][2048]    @ 8912896   (8388608 f)   k-order: k' = m*32 + 2c + (0 re/1 im)
// xb    bf16 [8192][1024]    @ 17301504  (4194304 f)
// gob   bf16 [1024][1024]    @ 21495808  (524288 f)
// skb   bf16 [1024][1024]    @ 22020096  (524288 f)
// mixb  bf16 [1024][2048]    @ 22544384  (1048576 f)   same permuted k-order as zinb
// zg    bf16 [8192][1024]    @ 23592960  (4194304 f)   [pwb/gwb borrow pre-gA]
// sk2   bf16 [8192][1024]    @ 27787264  (4194304 f)
// fstate fp32 [2048]         @ 31981568
// mask  u8   [8192]          @ 31983616  (2048 f)
// mask64 u64 [128]           @ 31985664  (256 f)

// ---------------- C0: fp32 -> bf16 conversions + start-mask normalize + bit-pack -------------
// (round-6 version: row-major gob/skb; mixb row-major over permuted k' = mm*32 + 2cc + p.
//  r7's fragment-major layout reverted with the gA revert.)
__global__ __launch_bounds__(256) void c0_conv(const float* __restrict__ x,
        const float* __restrict__ gw, const float* __restrict__ sw, const float* __restrict__ mw,
        const float* __restrict__ pw, const float* __restrict__ giw,
        const void* __restrict__ startp,
        unsigned short* __restrict__ xb, unsigned short* __restrict__ gob,
        unsigned short* __restrict__ skb, unsigned short* __restrict__ mixb,
        unsigned short* __restrict__ pwb, unsigned short* __restrict__ gwb,
        unsigned char* __restrict__ mask, unsigned long long* __restrict__ mask64)
{
    if (blockIdx.x == 0) {
        __shared__ int nonbool;
        int tid = threadIdx.x;
        if (tid == 0) nonbool = 0;
        __syncthreads();
        const unsigned int* wv = (const unsigned int*)startp;
        #pragma unroll
        for (int p = 0; p < 8; p++) {
            unsigned int a = wv[tid * 8 + p];
            if (a > 1u) nonbool = 1;
        }
        __syncthreads();
        if (nonbool) {
            const unsigned char* s8 = (const unsigned char*)startp;
            for (int i = tid; i < T_DIM; i += 256) mask[i] = (unsigned char)(s8[i] != 0);
        } else {
            const int* s32 = (const int*)startp;
            for (int i = tid; i < T_DIM; i += 256) mask[i] = (unsigned char)(s32[i] != 0);
        }
        __syncthreads();   // mask bytes visible block-wide; pack 64 bits/thread
        if (tid < 128) {
            unsigned long long wv2 = 0ull;
            int base = tid * 64;
            #pragma unroll 8
            for (int b2 = 0; b2 < 64; b2++)
                wv2 |= ((unsigned long long)(mask[base + b2] & 1)) << b2;
            mask64[tid] = wv2;
        }
    }
    // part A: straight conversions (x, go_w, skip_w, pre_w, gi_w)
    const size_t QX = 2097152, QG = 262144, QS = 262144, QP = 16384, QI = 16384;
    const size_t totalA = QX + QG + QS + QP + QI;   // 2654208
    for (size_t q = (size_t)blockIdx.x * blockDim.x + threadIdx.x; q < totalA;
         q += (size_t)gridDim.x * blockDim.x) {
        const float* src; unsigned short* dst; size_t i;
        if (q < QX)               { src = x;   dst = xb;   i = q; }
        else if (q < QX+QG)       { src = gw;  dst = gob;  i = q - QX; }
        else if (q < QX+QG+QS)    { src = sw;  dst = skb;  i = q - QX - QG; }
        else if (q < QX+QG+QS+QP) { src = pw;  dst = pwb;  i = q - QX - QG - QS; }
        else                      { src = giw; dst = gwb;  i = q - QX - QG - QS - QP; }
        float4 v = *(const float4*)(src + i * 4);
        ushort4 o;
        o.x = f2bf(v.x); o.y = f2bf(v.y); o.z = f2bf(v.z); o.w = f2bf(v.w);
        *(ushort4*)(dst + i * 4) = o;
    }
    // part B: mix_w with k-permutation: k = mm*32 + p*16 + cc -> k' = mm*32 + 2*cc + p
    const size_t QM = 524288;
    for (size_t q = (size_t)blockIdx.x * blockDim.x + threadIdx.x; q < QM;
         q += (size_t)gridDim.x * blockDim.x) {
        float4 v = *(const float4*)(mw + q * 4);
        int flat = (int)(q * 4);
        int n  = flat >> 11;
        int kk = flat & 2047;
        int mm = kk >> 5;
        int w_ = kk & 31;
        int p  = w_ >> 4;
        int cc = w_ & 15;            // multiple of 4 (flat is x4)
        int kb = (n << 11) + mm * 32 + (cc << 1) + p;
        mixb[kb]     = f2bf(v.x);
        mixb[kb + 2] = f2bf(v.y);
        mixb[kb + 4] = f2bf(v.z);
        mixb[kb + 6] = f2bf(v.w);
    }
}

// ---------------- K1: MFMA gated_x, 256 blocks of 32t x 128m, swizzled LDS --------------------
__global__ __launch_bounds__(256) void k1_mfma(const unsigned short* __restrict__ xb,
        const unsigned short* __restrict__ pwb, const unsigned short* __restrict__ gwb,
        const float* __restrict__ pre_b, const float* __restrict__ gi_b,
        float* __restrict__ gxT)
{
    __shared__ __align__(16) unsigned short As[1024];
    __shared__ __align__(16) unsigned short Bs[4096];
    __shared__ float sgE[64][33];

    const int tid = threadIdx.x;
    const int t0 = blockIdx.x * 32;
    const int lane = tid & 63, w = tid >> 6;
    const int quad = lane >> 4, l16 = lane & 15;
    const int r = tid >> 2, s4 = tid & 3;
    const int csw = (s4 - ((r >> 1) & 3)) & 3;

    f32x4 acc[2][2];
    const f32x4 zero4 = {0.f, 0.f, 0.f, 0.f};
    #pragma unroll
    for (int mi = 0; mi < 2; mi++)
        #pragma unroll
        for (int ni = 0; ni < 2; ni++) acc[mi][ni] = zero4;

    const int sfr = (quad + ((l16 >> 1) & 3)) & 3;

    for (int k0 = 0; k0 < IN_DIM; k0 += 32) {
        __syncthreads();
        if (tid < 128) {
            int ra = tid >> 2;
            int ca = ((tid & 3) - ((ra >> 1) & 3)) & 3;
            gl2lds16(xb + (size_t)(t0 + ra) * IN_DIM + k0 + ca * 8, As + tid * 8);
        }
        gl2lds16(pwb + (size_t)r * IN_DIM + k0 + csw * 8, Bs + tid * 8);
        gl2lds16(gwb + (size_t)r * IN_DIM + k0 + csw * 8, Bs + 2048 + tid * 8);
        asm volatile("s_waitcnt vmcnt(0)" ::: "memory");
        __syncthreads();
        bf16x8 af[2], bf[2];
        #pragma unroll
        for (int mi = 0; mi < 2; mi++)
            af[mi] = *(const bf16x8*)&As[(mi * 16 + l16) * 32 + sfr * 8];
        #pragma unroll
        for (int ni = 0; ni < 2; ni++)
            bf[ni] = *(const bf16x8*)&Bs[(w * 32 + ni * 16 + l16) * 32 + sfr * 8];
        #pragma unroll
        for (int mi = 0; mi < 2; mi++)
            #pragma unroll
            for (int ni = 0; ni < 2; ni++)
                acc[mi][ni] = __builtin_amdgcn_mfma_f32_16x16x32_bf16(af[mi], bf[ni], acc[mi][ni], 0, 0, 0);
    }

    if (w >= 2) {
        #pragma unroll
        for (int mi = 0; mi < 2; mi++)
            #pragma unroll
            for (int ni = 0; ni < 2; ni++) {
                int mg = (w - 2) * 32 + ni * 16 + l16;
                float gb = gi_b[mg];
                #pragma unroll
                for (int rr = 0; rr < 4; rr++) {
                    int tl = mi * 16 + quad * 4 + rr;
                    sgE[mg][tl] = 1.f / (1.f + expf(-(acc[mi][ni][rr] + gb)));
                }
            }
    }
    __syncthreads();
    if (w < 2) {
        #pragma unroll
        for (int mi = 0; mi < 2; mi++)
            #pragma unroll
            for (int ni = 0; ni < 2; ni++) {
                int mp = w * 32 + ni * 16 + l16;
                float pb = pre_b[mp];
                float4 o;
                float* po = &o.x;
                #pragma unroll
                for (int rr = 0; rr < 4; rr++) {
                    int tl = mi * 16 + quad * 4 + rr;
                    po[rr] = (acc[mi][ni][rr] + pb) * sgE[mp][tl];
                }
                *(float4*)&gxT[(size_t)mp * T_DIM + t0 + mi * 16 + quad * 4] = o;
            }
    }
}

// ---------------- K2: resettable complex scan, FULL-CHIP, direct zinb[t][k'] output -----------
__global__ __launch_bounds__(1024, 1) void k2_scan(const float* __restrict__ gxT,
        const unsigned long long* __restrict__ mask64,
        const float* __restrict__ state_re, const float* __restrict__ state_im,
        const float* __restrict__ ffa_a, const float* __restrict__ ffa_b,
        unsigned short* __restrict__ zinb, float* __restrict__ fstate)
{
    const int m  = blockIdx.x >> 2;
    const int qd = blockIdx.x & 3;             // quarter: t in [qd*2048, qd*2048+2048)
    const int tid = threadIdx.x;
    const int c = tid & 15, j = tid >> 4;      // j in [0,64): pass-1 chunk of 128 t
    __shared__ __align__(16) float gxs[8192 + 128];   // padded: idx = t + (t>>6)
    __shared__ float Br[16][65], Bi[16][65], Er[16][65], Ei[16][65];
    __shared__ unsigned char Rf[16][65];
    __shared__ float B32r[16][16][3], B32i[16][16][3];   // from-zero states after 32/64/96 t
    __shared__ unsigned char sRf[16][16][3];             // reset-in-prefix flags

    const float am = -fabsf(ffa_a[m]);
    const float bc = ffa_b[c];
    const float er = expf(am);
    const float gr = er * cosf(bc);
    const float gi = er * sinf(bc);

    {
        const float4* gx4 = (const float4*)(gxT + (size_t)m * T_DIM);
        #pragma unroll
        for (int it = 0; it < 2; it++) {
            int g = it * 1024 + tid;
            float4 v = gx4[g];
            int t = g * 4;
            gxs[t     + ( t      >> 6)] = v.x;
            gxs[t + 1 + ((t + 1) >> 6)] = v.y;
            gxs[t + 2 + ((t + 2) >> 6)] = v.z;
            gxs[t + 3 + ((t + 3) >> 6)] = v.w;
        }
    }
    const unsigned long long mw0 = mask64[j * 2];
    const unsigned long long mw1 = mask64[j * 2 + 1];
    __syncthreads();

    const int lb = j * 130;
    const int gloc = j - qd * 16;
    const bool own = (unsigned)gloc < 16u;

    float sre = 0.f, sim = 0.f;
    #pragma unroll 8
    for (int i = 0; i < 32; i++) {
        if ((mw0 >> i) & 1ull) { sre = 0.f; sim = 0.f; }
        else { float tr_ = sre * gr - sim * gi; sim = sre * gi + sim * gr; sre = tr_; }
        sre += gxs[lb + i];
    }
    if (own) { B32r[c][gloc][0] = sre; B32i[c][gloc][0] = sim;
               sRf[c][gloc][0] = ((mw0 & 0xffffffffull) != 0ull) ? 1 : 0; }
    #pragma unroll 8
    for (int i = 0; i < 32; i++) {
        if ((mw0 >> (i + 32)) & 1ull) { sre = 0.f; sim = 0.f; }
        else { float tr_ = sre * gr - sim * gi; sim = sre * gi + sim * gr; sre = tr_; }
        sre += gxs[lb + 32 + i];
    }
    if (own) { B32r[c][gloc][1] = sre; B32i[c][gloc][1] = sim;
               sRf[c][gloc][1] = (mw0 != 0ull) ? 1 : 0; }
    #pragma unroll 8
    for (int i = 0; i < 32; i++) {
        if ((mw1 >> i) & 1ull) { sre = 0.f; sim = 0.f; }
        else { float tr_ = sre * gr - sim * gi; sim = sre * gi + sim * gr; sre = tr_; }
        sre += gxs[lb + 65 + i];
    }
    if (own) { B32r[c][gloc][2] = sre; B32i[c][gloc][2] = sim;
               sRf[c][gloc][2] = ((mw0 != 0ull) || ((mw1 & 0xffffffffull) != 0ull)) ? 1 : 0; }
    #pragma unroll 8
    for (int i = 0; i < 32; i++) {
        if ((mw1 >> (i + 32)) & 1ull) { sre = 0.f; sim = 0.f; }
        else { float tr_ = sre * gr - sim * gi; sim = sre * gi + sim * gr; sre = tr_; }
        sre += gxs[lb + 97 + i];
    }
    Br[c][j] = sre; Bi[c][j] = sim; Rf[c][j] = ((mw0 | mw1) != 0ull) ? 1 : 0;
    __syncthreads();

    if (tid < 16) {
        const int cc = tid;
        float b2 = 128.f * ffa_b[cc];
        float e128 = expf(128.f * am);
        float gRr = e128 * cosf(b2);
        float gRi = e128 * sinf(b2);
        float pr = state_re[m * CTX + cc], pi = state_im[m * CTX + cc];
        for (int q2 = 0; q2 < 64; q2++) {
            Er[cc][q2] = pr; Ei[cc][q2] = pi;
            if (Rf[cc][q2]) { pr = Br[cc][q2]; pi = Bi[cc][q2]; }
            else {
                float nr = pr * gRr - pi * gRi + Br[cc][q2];
                pi       = pr * gRi + pi * gRr + Bi[cc][q2];
                pr = nr;
            }
        }
    }
    __syncthreads();

    {
        const int gl2 = j >> 2, s = j & 3;
        const int g = qd * 16 + gl2;
        const unsigned long long w0 = mask64[g * 2];
        const unsigned long long w1 = mask64[g * 2 + 1];
        const unsigned int mbits = (unsigned int)(((s < 2) ? w0 : w1) >> ((s & 1) * 32));
        float str, sti;
        {
            float E_r = Er[c][g], E_i = Ei[c][g];
            if (s == 0) { str = E_r; sti = E_i; }
            else if (sRf[c][gl2][s - 1]) { str = B32r[c][gl2][s - 1]; sti = B32i[c][gl2][s - 1]; }
            else {
                float ang = 32.f * (float)s * bc;
                float mag = expf(32.f * (float)s * am);
                float gsr = mag * cosf(ang), gsi = mag * sinf(ang);
                str = B32r[c][gl2][s - 1] + E_r * gsr - E_i * gsi;
                sti = B32i[c][gl2][s - 1] + E_r * gsi + E_i * gsr;
            }
        }
        const int pb = g * 130 + (s >> 1) * 65 + (s & 1) * 32;
        const int tstart = g * 128 + s * 32;
        unsigned int* zout = (unsigned int*)zinb;
        const int obase = m * CTX + c;
        #pragma unroll 8
        for (int i = 0; i < 32; i++) {
            if ((mbits >> i) & 1u) { str = 0.f; sti = 0.f; }
            else { float tr_ = str * gr - sti * gi; sti = str * gi + sti * gr; str = tr_; }
            str += gxs[pb + i];
            unsigned int u = (unsigned int)f2bf(str) | ((unsigned int)f2bf(sti) << 16);
            zout[((size_t)(tstart + i) << 10) + obase] = u;
        }
        if (qd == 3 && j == 63) {
            fstate[obase]        = str;
            fstate[1024 + obase] = sti;
        }
    }
}

// ---------------- GA: 128x128 tile, 4 waves, BK=32, triple-buffered, 2 blocks/CU --------------
// Round-8: controlled TLP test. r6's structure (barrier-locked 8 waves, 1 block/CU) kept
// MfmaUtil at 36%; r2's TLP attempt was confounded by tile-shrink traffic. This holds the
// per-wave MFMA:LDS ratio, acc count, and total FETCH/WRITE constant (BN stays 128, wave tile
// stays 64x64) and changes ONE variable: BM 256->128 with 72KB LDS -> grid 512 -> 2
// barrier-DECOUPLED blocks/CU. When one block's 4 waves park at their staging barrier, the
// other block's waves feed the MFMA pipe. (r7's global->reg B-loads reverted: exposed L2
// latency per tile, MfmaUtil 25.6%.)
__global__ __launch_bounds__(256, 2) void gA_gemm(
        const unsigned short* __restrict__ xb,   const unsigned short* __restrict__ zinb,
        const unsigned short* __restrict__ gob,  const unsigned short* __restrict__ skb,
        const unsigned short* __restrict__ mixb,
        const float* __restrict__ go_b, const float* __restrict__ skip_b, const float* __restrict__ mix_b,
        unsigned short* __restrict__ zg, unsigned short* __restrict__ sk2)
{
    __shared__ __align__(16) unsigned short L[36864];   // 3 buffers x (A 4096 | B 4096 | C 4096 ushorts)
    const int tid = threadIdx.x;
    const int b = blockIdx.x;
    const int xcd = b & 7, q = b >> 3;                  // q in [0,64)
    const int t0 = (xcd * 8 + (q >> 3)) * 128;          // 64 t-panels of 128 (XCD-contiguous)
    const int n0 = (q & 7) * 128;                       // 8 n-tiles of 128

    const int lane = tid & 63, w = tid >> 6;            // 4 waves
    const int wm = w >> 1, wn = w & 1;                  // 2 x 2 wave grid, wave tile 64x64
    const int l31 = lane & 31, h = lane >> 5;
    const int r = tid >> 2;                             // [0,64)
    const int csw = ((tid & 3) - ((r >> 1) & 3)) & 3;   // staging chunk permutation
    const int c8 = csw * 8;
    const int srot = (l31 >> 1) & 3;                    // fragment de-swizzle rotation
    const int dst8 = tid * 8;

    f32x16 accg[2][2], acck[2][2];
    #pragma unroll
    for (int mi = 0; mi < 2; mi++)
        #pragma unroll
        for (int ni = 0; ni < 2; ni++)
            #pragma unroll
            for (int e = 0; e < 16; e++) { accg[mi][ni][e] = 0.f; acck[mi][ni][e] = 0.f; }

    // ---- fused phase: go + skip (shared A = xb), K = 1024, 32 tiles of BK=32 ----
    {
        const unsigned short* gA0 = xb  + (size_t)(t0 + r)      * IN_DIM + c8;
        const unsigned short* gA1 = xb  + (size_t)(t0 + 64 + r) * IN_DIM + c8;
        const unsigned short* gB0 = gob + (size_t)(n0 + r)      * IN_DIM + c8;
        const unsigned short* gB1 = gob + (size_t)(n0 + 64 + r) * IN_DIM + c8;
        const unsigned short* gC0 = skb + (size_t)(n0 + r)      * IN_DIM + c8;
        const unsigned short* gC1 = skb + (size_t)(n0 + 64 + r) * IN_DIM + c8;

#define STAGE_F(bufi, kof) do {                         \
        unsigned short* _b = &L[(bufi) * 12288];        \
        gl2lds16(gA0 + (kof), _b + dst8);               \
        gl2lds16(gA1 + (kof), _b + 2048 + dst8);        \
        gl2lds16(gB0 + (kof), _b + 4096 + dst8);        \
        gl2lds16(gB1 + (kof), _b + 6144 + dst8);        \
        gl2lds16(gC0 + (kof), _b + 8192 + dst8);        \
        gl2lds16(gC1 + (kof), _b + 10240 + dst8);       \
    } while (0)

#define STEP_F(T, CUR, NXT, DOST, VMC) do {             \
        const unsigned short* As = &L[(CUR) * 12288];   \
        const unsigned short* Bs = As + 4096;           \
        const unsigned short* Cs = As + 8192;           \
        _Pragma("unroll")                               \
        for (int kh = 0; kh < 2; kh++) {                \
            const int so = ((kh * 2 + h + srot) & 3) * 8; \
            bf16x8 af[2], bg[2], bk[2];                 \
            _Pragma("unroll")                           \
            for (int mi = 0; mi < 2; mi++)              \
                af[mi] = *(const bf16x8*)&As[(wm * 64 + mi * 32 + l31) * 32 + so]; \
            _Pragma("unroll")                           \
            for (int ni = 0; ni < 2; ni++) {            \
                bg[ni] = *(const bf16x8*)&Bs[(wn * 64 + ni * 32 + l31) * 32 + so]; \
                bk[ni] = *(const bf16x8*)&Cs[(wn * 64 + ni * 32 + l31) * 32 + so]; \
            }                                           \
            if (kh == 0 && (DOST)) STAGE_F(NXT, ((T) + 2) * 32); \
            __builtin_amdgcn_s_setprio(1);              \
            _Pragma("unroll")                           \
            for (int mi = 0; mi < 2; mi++)              \
                _Pragma("unroll")                       \
                for (int ni = 0; ni < 2; ni++) {        \
                    accg[mi][ni] = __builtin_amdgcn_mfma_f32_32x32x16_bf16(af[mi], bg[ni], accg[mi][ni], 0, 0, 0); \
                    acck[mi][ni] = __builtin_amdgcn_mfma_f32_32x32x16_bf16(af[mi], bk[ni], acck[mi][ni], 0, 0, 0); \
                }                                       \
            __builtin_amdgcn_s_setprio(0);              \
        }                                               \
        asm volatile("s_waitcnt vmcnt(" #VMC ")" ::: "memory"); \
        __builtin_amdgcn_s_barrier();                   \
    } while (0)

        STAGE_F(0, 0);
        STAGE_F(1, 32);
        asm volatile("s_waitcnt vmcnt(6)" ::: "memory");
        __builtin_amdgcn_s_barrier();

        for (int t3i = 0; t3i < 30; t3i += 3) {
            STEP_F(t3i,     0, 2, 1, 6);
            STEP_F(t3i + 1, 1, 0, 1, 6);
            STEP_F(t3i + 2, 2, 1, 1, 6);
        }
        STEP_F(30, 0, 2, 0, 0);
        STEP_F(31, 1, 0, 0, 0);
#undef STEP_F
#undef STAGE_F
    }

    // sigmoid (packed bf16 pairs) + sk2 write
    unsigned int sigp[32];
    #pragma unroll
    for (int mi = 0; mi < 2; mi++)
        #pragma unroll
        for (int ni = 0; ni < 2; ni++) {
            int n = n0 + wn * 64 + ni * 32 + l31;
            float gb = go_b[n];
            float sb_ = skip_b[n];
            #pragma unroll
            for (int reg = 0; reg < 16; reg++) {
                int row = (reg & 3) + 8 * (reg >> 2) + 4 * h;
                int t = t0 + wm * 64 + mi * 32 + row;
                float s = 1.f / (1.f + expf(-(accg[mi][ni][reg] + gb)));
                sk2[(size_t)t * OUT_DIM + n] = f2bf((acck[mi][ni][reg] + sb_) * (1.f - s));
                unsigned int pk = (unsigned int)f2bf(s);
                int idx = (mi * 2 + ni) * 8 + (reg >> 1);
                if (reg & 1) sigp[idx] |= pk << 16;
                else         sigp[idx]  = pk;
            }
        }

    // ---- mix phase, K = 2048, 64 tiles of BK=32 ----
    #pragma unroll
    for (int mi = 0; mi < 2; mi++)
        #pragma unroll
        for (int ni = 0; ni < 2; ni++)
            #pragma unroll
            for (int e = 0; e < 16; e++) accg[mi][ni][e] = 0.f;
    {
        const unsigned short* mA0 = zinb + (size_t)(t0 + r)      * KMIX + c8;
        const unsigned short* mA1 = zinb + (size_t)(t0 + 64 + r) * KMIX + c8;
        const unsigned short* mB0 = mixb + (size_t)(n0 + r)      * KMIX + c8;
        const unsigned short* mB1 = mixb + (size_t)(n0 + 64 + r) * KMIX + c8;

#define STAGE_M(bufi, kof) do {                         \
        unsigned short* _b = &L[(bufi) * 12288];        \
        gl2lds16(mA0 + (kof), _b + dst8);               \
        gl2lds16(mA1 + (kof), _b + 2048 + dst8);        \
        gl2lds16(mB0 + (kof), _b + 4096 + dst8);        \
        gl2lds16(mB1 + (kof), _b + 6144 + dst8);        \
    } while (0)

#define STEP_M(T, CUR, NXT, DOST, VMC) do {             \
        const unsigned short* As = &L[(CUR) * 12288];   \
        const unsigned short* Bs = As + 4096;           \
        _Pragma("unroll")                               \
        for (int kh = 0; kh < 2; kh++) {                \
            const int so = ((kh * 2 + h + srot) & 3) * 8; \
            bf16x8 af[2], bf[2];                        \
            _Pragma("unroll")                           \
            for (int mi = 0; mi < 2; mi++)              \
                af[mi] = *(const bf16x8*)&As[(wm * 64 + mi * 32 + l31) * 32 + so]; \
            _Pragma("unroll")                           \
            for (int ni = 0; ni < 2; ni++)              \
                bf[ni] = *(const bf16x8*)&Bs[(wn * 64 + ni * 32 + l31) * 32 + so]; \
            if (kh == 0 && (DOST)) STAGE_M(NXT, ((T) + 2) * 32); \
            __builtin_amdgcn_s_setprio(1);              \
            _Pragma("unroll")                           \
            for (int mi = 0; mi < 2; mi++)              \
                _Pragma("unroll")                       \
                for (int ni = 0; ni < 2; ni++)          \
                    accg[mi][ni] = __builtin_amdgcn_mfma_f32_32x32x16_bf16(af[mi], bf[ni], accg[mi][ni], 0, 0, 0); \
            __builtin_amdgcn_s_setprio(0);              \
        }                                               \
        asm volatile("s_waitcnt vmcnt(" #VMC ")" ::: "memory"); \
        __builtin_amdgcn_s_barrier();                   \
    } while (0)

        STAGE_M(0, 0);
        STAGE_M(1, 32);
        asm volatile("s_waitcnt vmcnt(4)" ::: "memory");
        __builtin_amdgcn_s_barrier();

        for (int t3i = 0; t3i < 60; t3i += 3) {
            STEP_M(t3i,     0, 2, 1, 4);
            STEP_M(t3i + 1, 1, 0, 1, 4);
            STEP_M(t3i + 2, 2, 1, 1, 4);
        }
        STEP_M(60, 0, 2, 1, 4);
        STEP_M(61, 1, 0, 1, 4);
        STEP_M(62, 2, 1, 0, 0);
        STEP_M(63, 0, 2, 0, 0);
#undef STEP_M
#undef STAGE_M
    }

    #pragma unroll
    for (int mi = 0; mi < 2; mi++)
        #pragma unroll
        for (int ni = 0; ni < 2; ni++) {
            int n = n0 + wn * 64 + ni * 32 + l31;
            float mb_ = mix_b[n];
            #pragma unroll
            for (int reg = 0; reg < 16; reg++) {
                int row = (reg & 3) + 8 * (reg >> 2) + 4 * h;
                int t = t0 + wm * 64 + mi * 32 + row;
                unsigned int u = sigp[(mi * 2 + ni) * 8 + (reg >> 1)];
                float sig = bf2f((unsigned short)((reg & 1) ? (u >> 16) : (u & 0xffff)));
                zg[(size_t)t * OUT_DIM + n] = f2bf((accg[mi][ni][reg] + mb_) * sig);
            }
        }
}

// ---------------- G3: LayerNorm + residual (bf16 in, fp32 out) + final_state copy ------------
__global__ __launch_bounds__(256) void g3_ln(const unsigned short* __restrict__ zg,
        const unsigned short* __restrict__ sk2, const float* __restrict__ fstate,
        float* __restrict__ out, int out_size)
{
    __shared__ float sb[4], qb[4];
    __shared__ float mu_s, rstd_s;
    const int t = blockIdx.x;
    const int tid = threadIdx.x;
    ushort4 zu = *(const ushort4*)&zg [(size_t)t * OUT_DIM + tid * 4];
    ushort4 su = *(const ushort4*)&sk2[(size_t)t * OUT_DIM + tid * 4];
    float z0 = bf2f(zu.x), z1 = bf2f(zu.y), z2 = bf2f(zu.z), z3 = bf2f(zu.w);
    float s0 = bf2f(su.x), s1 = bf2f(su.y), s2 = bf2f(su.z), s3 = bf2f(su.w);
    float s = z0 + z1 + z2 + z3;
    float q = z0*z0 + z1*z1 + z2*z2 + z3*z3;
    #pragma unroll
    for (int off = 32; off > 0; off >>= 1) {
        s += __shfl_down(s, off, 64);
        q += __shfl_down(q, off, 64);
    }
    int wid = tid >> 6;
    if ((tid & 63) == 0) { sb[wid] = s; qb[wid] = q; }
    __syncthreads();
    if (tid == 0) {
        float S = sb[0] + sb[1] + sb[2] + sb[3];
        float Q = qb[0] + qb[1] + qb[2] + qb[3];
        float mu = S * (1.f / 1024.f);
        float var = Q * (1.f / 1024.f) - mu * mu;
        mu_s = mu; rstd_s = rsqrtf(var + 1e-5f);
    }
    __syncthreads();
    float mu = mu_s, rs = rstd_s;
    float4 o;
    o.x = (z0 - mu) * rs + s0;
    o.y = (z1 - mu) * rs + s1;
    o.z = (z2 - mu) * rs + s2;
    o.w = (z3 - mu) * rs + s3;
    *(float4*)&out[(size_t)t * OUT_DIM + tid * 4] = o;

    if (t < 8) {   // folded g4: final_state copy
        int i = t * 256 + tid;
        long long base = (long long)T_DIM * OUT_DIM;
        if (base + i < (long long)out_size) out[base + i] = fstate[i];
    }
}

extern "C" void kernel_launch(void* const* d_in, const int* in_sizes, int n_in,
                              void* d_out, int out_size, void* d_ws, size_t ws_size,
                              hipStream_t stream) {
    const float* x        = (const float*)d_in[0];
    const float* state_re = (const float*)d_in[1];
    const float* state_im = (const float*)d_in[2];
    const void*  startp   = d_in[3];
    const float* pre_w    = (const float*)d_in[5];
    const float* pre_b    = (const float*)d_in[6];
    const float* gi_w     = (const float*)d_in[7];
    const float* gi_b     = (const float*)d_in[8];
    const float* go_w     = (const float*)d_in[9];
    const float* go_b     = (const float*)d_in[10];
    const float* skip_w   = (const float*)d_in[11];
    const float* skip_b   = (const float*)d_in[12];
    const float* mix_w    = (const float*)d_in[13];
    const float* mix_b    = (const float*)d_in[14];
    const float* ffa_a    = (const float*)d_in[15];
    const float* ffa_b    = (const float*)d_in[16];

    float* ws = (float*)d_ws;
    float*          gxT    = ws;
    unsigned short* zinb   = (unsigned short*)(ws + 8912896);
    unsigned short* xb     = (unsigned short*)(ws + 17301504);
    unsigned short* gob    = (unsigned short*)(ws + 21495808);
    unsigned short* skb    = (unsigned short*)(ws + 22020096);
    unsigned short* mixb   = (unsigned short*)(ws + 22544384);
    unsigned short* zg     = (unsigned short*)(ws + 23592960);
    unsigned short* sk2    = (unsigned short*)(ws + 27787264);
    float*          fstate = ws + 31981568;
    unsigned char*  mask   = (unsigned char*)(ws + 31983616);
    unsigned long long* mask64 = (unsigned long long*)(ws + 31985664);
    unsigned short* pwb    = zg;            // borrow zg region pre-gA
    unsigned short* gwb    = zg + 65536;
    float* out = (float*)d_out;

    hipLaunchKernelGGL(c0_conv,  dim3(1536), dim3(256),  0, stream, x, go_w, skip_w, mix_w, pre_w, gi_w,
                                                          startp, xb, gob, skb, mixb, pwb, gwb, mask, mask64);
    hipLaunchKernelGGL(k1_mfma,  dim3(256),  dim3(256),  0, stream, xb, pwb, gwb, pre_b, gi_b, gxT);
    hipLaunchKernelGGL(k2_scan,  dim3(256),  dim3(1024), 0, stream, gxT, mask64, state_re, state_im, ffa_a, ffa_b, zinb, fstate);
    hipLaunchKernelGGL(gA_gemm,  dim3(512),  dim3(256),  0, stream, xb, zinb, gob, skb, mixb, go_b, skip_b, mix_b, zg, sk2);
    hipLaunchKernelGGL(g3_ln,    dim3(8192), dim3(256),  0, stream, zg, sk2, fstate, out, out_size);
}

// Round 10
// 258.452 us; speedup vs baseline: 1.1153x; 1.0178x over previous
//
#include <hip/hip_runtime.h>
#include <math.h>

#define T_DIM 8192
#define IN_DIM 1024
#define TRACE 64
#define CTX 16
#define OUT_DIM 1024
#define KMIX 2048

typedef __attribute__((ext_vector_type(8))) short bf16x8;
typedef __attribute__((ext_vector_type(8))) unsigned short u16x8;
typedef __attribute__((ext_vector_type(4))) float f32x4;
typedef __attribute__((ext_vector_type(16))) float f32x16;

__device__ __forceinline__ unsigned short f2bf(float f) {
    unsigned int u = __float_as_uint(f);
    u = (u + 0x7FFFu + ((u >> 16) & 1u)) >> 16;
    return (unsigned short)u;
}
__device__ __forceinline__ float bf2f(unsigned short b) {
    return __uint_as_float(((unsigned int)b) << 16);
}

__device__ __forceinline__ void gl2lds16(const void* g, void* l) {
    __builtin_amdgcn_global_load_lds(
        (const __attribute__((address_space(1))) unsigned int*)g,
        (__attribute__((address_space(3))) unsigned int*)l,
        16, 0, 0);
}

// ---------------- ws layout (float offsets) ----------------
// gxT   fp32 [64][8192]      @ 0         (524288 f)
// zinb  bf16 [8192][2048]    @ 8912896   (8388608 f)   k-order: k' = m*32 + 2c + (0 re/1 im)
// xb    bf16 [8192][1024]    @ 17301504  (4194304 f)
// gob   bf16 [1024][1024]    @ 21495808  (524288 f)
// skb   bf16 [1024][1024]    @ 22020096  (524288 f)
// mixb  bf16 [1024][2048]    @ 22544384  (1048576 f)   same permuted k-order as zinb
// zg    bf16 [8192][1024]    @ 23592960  (4194304 f)   [pwb/gwb borrow pre-gA]
// sk2   bf16 [8192][1024]    @ 27787264  (4194304 f)
// fstate fp32 [2048]         @ 31981568
// mask  u8   [8192]          @ 31983616  (2048 f)
// mask64 u64 [128]           @ 31985664  (256 f)

// ---------------- C0: fp32 -> bf16 conversions + start-mask normalize + bit-pack -------------
// part B reads BOTH p-halves per thread and emits one contiguous 16B store:
// k = mm*32 + p*16 + cc -> k' = mm*32 + 2*cc + p.
// ROUND-10 FIX: QM2 was 131072 (covered only mm 0..31 -> half of mixb stale, absmax 6.4).
// Correct thread count: 2097152 elems / 8 per thread = 262144; rem = q&255 -> mm in [0,64).
__global__ __launch_bounds__(256) void c0_conv(const float* __restrict__ x,
        const float* __restrict__ gw, const float* __restrict__ sw, const float* __restrict__ mw,
        const float* __restrict__ pw, const float* __restrict__ giw,
        const void* __restrict__ startp,
        unsigned short* __restrict__ xb, unsigned short* __restrict__ gob,
        unsigned short* __restrict__ skb, unsigned short* __restrict__ mixb,
        unsigned short* __restrict__ pwb, unsigned short* __restrict__ gwb,
        unsigned char* __restrict__ mask, unsigned long long* __restrict__ mask64)
{
    if (blockIdx.x == 0) {
        __shared__ int nonbool;
        int tid = threadIdx.x;
        if (tid == 0) nonbool = 0;
        __syncthreads();
        const unsigned int* wv = (const unsigned int*)startp;
        #pragma unroll
        for (int p = 0; p < 8; p++) {
            unsigned int a = wv[tid * 8 + p];
            if (a > 1u) nonbool = 1;
        }
        __syncthreads();
        if (nonbool) {
            const unsigned char* s8 = (const unsigned char*)startp;
            for (int i = tid; i < T_DIM; i += 256) mask[i] = (unsigned char)(s8[i] != 0);
        } else {
            const int* s32 = (const int*)startp;
            for (int i = tid; i < T_DIM; i += 256) mask[i] = (unsigned char)(s32[i] != 0);
        }
        __syncthreads();   // mask bytes visible block-wide; pack 64 bits/thread
        if (tid < 128) {
            unsigned long long wv2 = 0ull;
            int base = tid * 64;
            #pragma unroll 8
            for (int b2 = 0; b2 < 64; b2++)
                wv2 |= ((unsigned long long)(mask[base + b2] & 1)) << b2;
            mask64[tid] = wv2;
        }
    }
    // part A: straight conversions (x, go_w, skip_w, pre_w, gi_w)
    const size_t QX = 2097152, QG = 262144, QS = 262144, QP = 16384, QI = 16384;
    const size_t totalA = QX + QG + QS + QP + QI;   // 2654208
    for (size_t q = (size_t)blockIdx.x * blockDim.x + threadIdx.x; q < totalA;
         q += (size_t)gridDim.x * blockDim.x) {
        const float* src; unsigned short* dst; size_t i;
        if (q < QX)               { src = x;   dst = xb;   i = q; }
        else if (q < QX+QG)       { src = gw;  dst = gob;  i = q - QX; }
        else if (q < QX+QG+QS)    { src = sw;  dst = skb;  i = q - QX - QG; }
        else if (q < QX+QG+QS+QP) { src = pw;  dst = pwb;  i = q - QX - QG - QS; }
        else                      { src = giw; dst = gwb;  i = q - QX - QG - QS - QP; }
        float4 v = *(const float4*)(src + i * 4);
        ushort4 o;
        o.x = f2bf(v.x); o.y = f2bf(v.y); o.z = f2bf(v.z); o.w = f2bf(v.w);
        *(ushort4*)(dst + i * 4) = o;
    }
    // part B: mix_w permutation with 16B stores.
    // thread q: n = q>>8, mm = (q&255)>>2, c4 = (q&3)*4; reads p0/p1 float4s, writes ushort8
    // at row offset mm*32 + 2*c4 with interleave [p0c0,p1c0,p0c1,p1c1,...].
    const size_t QM2 = 262144;
    for (size_t q = (size_t)blockIdx.x * blockDim.x + threadIdx.x; q < QM2;
         q += (size_t)gridDim.x * blockDim.x) {
        int n   = (int)(q >> 8);
        int rem = (int)(q & 255);
        int mm  = rem >> 2;
        int c4  = (rem & 3) << 2;
        const float* base = mw + (size_t)n * 2048 + mm * 32;
        float4 v0 = *(const float4*)(base + c4);        // p=0, cc = c4..c4+3
        float4 v1 = *(const float4*)(base + 16 + c4);   // p=1
        u16x8 o;
        o[0] = f2bf(v0.x); o[1] = f2bf(v1.x);
        o[2] = f2bf(v0.y); o[3] = f2bf(v1.y);
        o[4] = f2bf(v0.z); o[5] = f2bf(v1.z);
        o[6] = f2bf(v0.w); o[7] = f2bf(v1.w);
        *(u16x8*)(mixb + (size_t)n * 2048 + mm * 32 + c4 * 2) = o;
    }
}

// ---------------- K1: MFMA gated_x, 256 blocks of 32t x 128m, swizzled LDS --------------------
__global__ __launch_bounds__(256) void k1_mfma(const unsigned short* __restrict__ xb,
        const unsigned short* __restrict__ pwb, const unsigned short* __restrict__ gwb,
        const float* __restrict__ pre_b, const float* __restrict__ gi_b,
        float* __restrict__ gxT)
{
    __shared__ __align__(16) unsigned short As[1024];
    __shared__ __align__(16) unsigned short Bs[4096];
    __shared__ float sgE[64][33];

    const int tid = threadIdx.x;
    const int t0 = blockIdx.x * 32;
    const int lane = tid & 63, w = tid >> 6;
    const int quad = lane >> 4, l16 = lane & 15;
    const int r = tid >> 2, s4 = tid & 3;
    const int csw = (s4 - ((r >> 1) & 3)) & 3;

    f32x4 acc[2][2];
    const f32x4 zero4 = {0.f, 0.f, 0.f, 0.f};
    #pragma unroll
    for (int mi = 0; mi < 2; mi++)
        #pragma unroll
        for (int ni = 0; ni < 2; ni++) acc[mi][ni] = zero4;

    const int sfr = (quad + ((l16 >> 1) & 3)) & 3;

    for (int k0 = 0; k0 < IN_DIM; k0 += 32) {
        __syncthreads();
        if (tid < 128) {
            int ra = tid >> 2;
            int ca = ((tid & 3) - ((ra >> 1) & 3)) & 3;
            gl2lds16(xb + (size_t)(t0 + ra) * IN_DIM + k0 + ca * 8, As + tid * 8);
        }
        gl2lds16(pwb + (size_t)r * IN_DIM + k0 + csw * 8, Bs + tid * 8);
        gl2lds16(gwb + (size_t)r * IN_DIM + k0 + csw * 8, Bs + 2048 + tid * 8);
        asm volatile("s_waitcnt vmcnt(0)" ::: "memory");
        __syncthreads();
        bf16x8 af[2], bf[2];
        #pragma unroll
        for (int mi = 0; mi < 2; mi++)
            af[mi] = *(const bf16x8*)&As[(mi * 16 + l16) * 32 + sfr * 8];
        #pragma unroll
        for (int ni = 0; ni < 2; ni++)
            bf[ni] = *(const bf16x8*)&Bs[(w * 32 + ni * 16 + l16) * 32 + sfr * 8];
        #pragma unroll
        for (int mi = 0; mi < 2; mi++)
            #pragma unroll
            for (int ni = 0; ni < 2; ni++)
                acc[mi][ni] = __builtin_amdgcn_mfma_f32_16x16x32_bf16(af[mi], bf[ni], acc[mi][ni], 0, 0, 0);
    }

    if (w >= 2) {
        #pragma unroll
        for (int mi = 0; mi < 2; mi++)
            #pragma unroll
            for (int ni = 0; ni < 2; ni++) {
                int mg = (w - 2) * 32 + ni * 16 + l16;
                float gb = gi_b[mg];
                #pragma unroll
                for (int rr = 0; rr < 4; rr++) {
                    int tl = mi * 16 + quad * 4 + rr;
                    sgE[mg][tl] = 1.f / (1.f + expf(-(acc[mi][ni][rr] + gb)));
                }
            }
    }
    __syncthreads();
    if (w < 2) {
        #pragma unroll
        for (int mi = 0; mi < 2; mi++)
            #pragma unroll
            for (int ni = 0; ni < 2; ni++) {
                int mp = w * 32 + ni * 16 + l16;
                float pb = pre_b[mp];
                float4 o;
                float* po = &o.x;
                #pragma unroll
                for (int rr = 0; rr < 4; rr++) {
                    int tl = mi * 16 + quad * 4 + rr;
                    po[rr] = (acc[mi][ni][rr] + pb) * sgE[mp][tl];
                }
                *(float4*)&gxT[(size_t)mp * T_DIM + t0 + mi * 16 + quad * 4] = o;
            }
    }
}

// ---------------- K2: resettable complex scan, FULL-CHIP, direct zinb[t][k'] output -----------
__global__ __launch_bounds__(1024, 1) void k2_scan(const float* __restrict__ gxT,
        const unsigned long long* __restrict__ mask64,
        const float* __restrict__ state_re, const float* __restrict__ state_im,
        const float* __restrict__ ffa_a, const float* __restrict__ ffa_b,
        unsigned short* __restrict__ zinb, float* __restrict__ fstate)
{
    const int m  = blockIdx.x >> 2;
    const int qd = blockIdx.x & 3;             // quarter: t in [qd*2048, qd*2048+2048)
    const int tid = threadIdx.x;
    const int c = tid & 15, j = tid >> 4;      // j in [0,64): pass-1 chunk of 128 t
    __shared__ __align__(16) float gxs[8192 + 128];   // padded: idx = t + (t>>6)
    __shared__ float Br[16][65], Bi[16][65], Er[16][65], Ei[16][65];
    __shared__ unsigned char Rf[16][65];
    __shared__ float B32r[16][16][3], B32i[16][16][3];   // from-zero states after 32/64/96 t
    __shared__ unsigned char sRf[16][16][3];             // reset-in-prefix flags

    const float am = -fabsf(ffa_a[m]);
    const float bc = ffa_b[c];
    const float er = expf(am);
    const float gr = er * cosf(bc);
    const float gi = er * sinf(bc);

    {
        const float4* gx4 = (const float4*)(gxT + (size_t)m * T_DIM);
        #pragma unroll
        for (int it = 0; it < 2; it++) {
            int g = it * 1024 + tid;
            float4 v = gx4[g];
            int t = g * 4;
            gxs[t     + ( t      >> 6)] = v.x;
            gxs[t + 1 + ((t + 1) >> 6)] = v.y;
            gxs[t + 2 + ((t + 2) >> 6)] = v.z;
            gxs[t + 3 + ((t + 3) >> 6)] = v.w;
        }
    }
    const unsigned long long mw0 = mask64[j * 2];
    const unsigned long long mw1 = mask64[j * 2 + 1];
    __syncthreads();

    const int lb = j * 130;
    const int gloc = j - qd * 16;
    const bool own = (unsigned)gloc < 16u;

    float sre = 0.f, sim = 0.f;
    #pragma unroll 8
    for (int i = 0; i < 32; i++) {
        if ((mw0 >> i) & 1ull) { sre = 0.f; sim = 0.f; }
        else { float tr_ = sre * gr - sim * gi; sim = sre * gi + sim * gr; sre = tr_; }
        sre += gxs[lb + i];
    }
    if (own) { B32r[c][gloc][0] = sre; B32i[c][gloc][0] = sim;
               sRf[c][gloc][0] = ((mw0 & 0xffffffffull) != 0ull) ? 1 : 0; }
    #pragma unroll 8
    for (int i = 0; i < 32; i++) {
        if ((mw0 >> (i + 32)) & 1ull) { sre = 0.f; sim = 0.f; }
        else { float tr_ = sre * gr - sim * gi; sim = sre * gi + sim * gr; sre = tr_; }
        sre += gxs[lb + 32 + i];
    }
    if (own) { B32r[c][gloc][1] = sre; B32i[c][gloc][1] = sim;
               sRf[c][gloc][1] = (mw0 != 0ull) ? 1 : 0; }
    #pragma unroll 8
    for (int i = 0; i < 32; i++) {
        if ((mw1 >> i) & 1ull) { sre = 0.f; sim = 0.f; }
        else { float tr_ = sre * gr - sim * gi; sim = sre * gi + sim * gr; sre = tr_; }
        sre += gxs[lb + 65 + i];
    }
    if (own) { B32r[c][gloc][2] = sre; B32i[c][gloc][2] = sim;
               sRf[c][gloc][2] = ((mw0 != 0ull) || ((mw1 & 0xffffffffull) != 0ull)) ? 1 : 0; }
    #pragma unroll 8
    for (int i = 0; i < 32; i++) {
        if ((mw1 >> (i + 32)) & 1ull) { sre = 0.f; sim = 0.f; }
        else { float tr_ = sre * gr - sim * gi; sim = sre * gi + sim * gr; sre = tr_; }
        sre += gxs[lb + 97 + i];
    }
    Br[c][j] = sre; Bi[c][j] = sim; Rf[c][j] = ((mw0 | mw1) != 0ull) ? 1 : 0;
    __syncthreads();

    if (tid < 16) {
        const int cc = tid;
        float b2 = 128.f * ffa_b[cc];
        float e128 = expf(128.f * am);
        float gRr = e128 * cosf(b2);
        float gRi = e128 * sinf(b2);
        float pr = state_re[m * CTX + cc], pi = state_im[m * CTX + cc];
        for (int q2 = 0; q2 < 64; q2++) {
            Er[cc][q2] = pr; Ei[cc][q2] = pi;
            if (Rf[cc][q2]) { pr = Br[cc][q2]; pi = Bi[cc][q2]; }
            else {
                float nr = pr * gRr - pi * gRi + Br[cc][q2];
                pi       = pr * gRi + pi * gRr + Bi[cc][q2];
                pr = nr;
            }
        }
    }
    __syncthreads();

    {
        const int gl2 = j >> 2, s = j & 3;
        const int g = qd * 16 + gl2;
        const unsigned long long w0 = mask64[g * 2];
        const unsigned long long w1 = mask64[g * 2 + 1];
        const unsigned int mbits = (unsigned int)(((s < 2) ? w0 : w1) >> ((s & 1) * 32));
        float str, sti;
        {
            float E_r = Er[c][g], E_i = Ei[c][g];
            if (s == 0) { str = E_r; sti = E_i; }
            else if (sRf[c][gl2][s - 1]) { str = B32r[c][gl2][s - 1]; sti = B32i[c][gl2][s - 1]; }
            else {
                float ang = 32.f * (float)s * bc;
                float mag = expf(32.f * (float)s * am);
                float gsr = mag * cosf(ang), gsi = mag * sinf(ang);
                str = B32r[c][gl2][s - 1] + E_r * gsr - E_i * gsi;
                sti = B32i[c][gl2][s - 1] + E_r * gsi + E_i * gsr;
            }
        }
        const int pb = g * 130 + (s >> 1) * 65 + (s & 1) * 32;
        const int tstart = g * 128 + s * 32;
        unsigned int* zout = (unsigned int*)zinb;
        const int obase = m * CTX + c;
        #pragma unroll 8
        for (int i = 0; i < 32; i++) {
            if ((mbits >> i) & 1u) { str = 0.f; sti = 0.f; }
            else { float tr_ = str * gr - sti * gi; sti = str * gi + sti * gr; str = tr_; }
            str += gxs[pb + i];
            unsigned int u = (unsigned int)f2bf(str) | ((unsigned int)f2bf(sti) << 16);
            zout[((size_t)(tstart + i) << 10) + obase] = u;
        }
        if (qd == 3 && j == 63) {
            fstate[obase]        = str;
            fstate[1024 + obase] = sti;
        }
    }
}

// ---------------- GA: 256x128 tile, 8 waves, BK=32, triple-buffered depth-2 prefetch ----------
// (r6 version verbatim - best measured 82 us. r7 reg-B-loads and r8 2-block TLP both null/neg.)
__global__ __launch_bounds__(512, 2) void gA_gemm(
        const unsigned short* __restrict__ xb,   const unsigned short* __restrict__ zinb,
        const unsigned short* __restrict__ gob,  const unsigned short* __restrict__ skb,
        const unsigned short* __restrict__ mixb,
        const float* __restrict__ go_b, const float* __restrict__ skip_b, const float* __restrict__ mix_b,
        unsigned short* __restrict__ zg, unsigned short* __restrict__ sk2)
{
    __shared__ __align__(16) unsigned short L[49152];   // 3 buffers x (A 8192 | B 4096 | C 4096)
    const int tid = threadIdx.x;
    const int b = blockIdx.x;
    const int xcd = b & 7, q = b >> 3;                  // q in [0,32)
    const int t0 = (xcd * 4 + (q >> 3)) * 256;          // 32 t-tiles of 256 (XCD-contiguous)
    const int n0 = (q & 7) * 128;                       // 8 n-tiles of 128

    const int lane = tid & 63, w = tid >> 6;            // 8 waves
    const int wm = w >> 1, wn = w & 1;                  // 4 x 2 wave grid, wave tile 64x64
    const int l31 = lane & 31, h = lane >> 5;
    const int r = tid >> 2;                             // [0,128)
    const int csw = ((tid & 3) - ((r >> 1) & 3)) & 3;   // staging chunk permutation
    const int c8 = csw * 8;
    const int srot = (l31 >> 1) & 3;                    // fragment de-swizzle rotation
    const int dst8 = tid * 8;

    f32x16 accg[2][2], acck[2][2];
    #pragma unroll
    for (int mi = 0; mi < 2; mi++)
        #pragma unroll
        for (int ni = 0; ni < 2; ni++)
            #pragma unroll
            for (int e = 0; e < 16; e++) { accg[mi][ni][e] = 0.f; acck[mi][ni][e] = 0.f; }

    // ---- fused phase: go + skip (shared A = xb), K = 1024, 32 tiles of BK=32 ----
    {
        const unsigned short* gA0 = xb  + (size_t)(t0 + r)       * IN_DIM + c8;
        const unsigned short* gA1 = xb  + (size_t)(t0 + 128 + r) * IN_DIM + c8;
        const unsigned short* gB0 = gob + (size_t)(n0 + r)       * IN_DIM + c8;
        const unsigned short* gC0 = skb + (size_t)(n0 + r)       * IN_DIM + c8;

#define STAGE_F(bufi, kof) do {                         \
        unsigned short* _b = &L[(bufi) * 16384];        \
        gl2lds16(gA0 + (kof), _b + dst8);               \
        gl2lds16(gA1 + (kof), _b + 4096 + dst8);        \
        gl2lds16(gB0 + (kof), _b + 8192 + dst8);        \
        gl2lds16(gC0 + (kof), _b + 12288 + dst8);       \
    } while (0)

#define STEP_F(T, CUR, NXT, DOST, VMC) do {             \
        const unsigned short* As = &L[(CUR) * 16384];   \
        const unsigned short* Bs = As + 8192;           \
        const unsigned short* Cs = As + 12288;          \
        _Pragma("unroll")                               \
        for (int kh = 0; kh < 2; kh++) {                \
            const int so = ((kh * 2 + h + srot) & 3) * 8; \
            bf16x8 af[2], bg[2], bk[2];                 \
            _Pragma("unroll")                           \
            for (int mi = 0; mi < 2; mi++)              \
                af[mi] = *(const bf16x8*)&As[(wm * 64 + mi * 32 + l31) * 32 + so]; \
            _Pragma("unroll")                           \
            for (int ni = 0; ni < 2; ni++) {            \
                bg[ni] = *(const bf16x8*)&Bs[(wn * 64 + ni * 32 + l31) * 32 + so]; \
                bk[ni] = *(const bf16x8*)&Cs[(wn * 64 + ni * 32 + l31) * 32 + so]; \
            }                                           \
            if (kh == 0 && (DOST)) STAGE_F(NXT, ((T) + 2) * 32); \
            __builtin_amdgcn_s_setprio(1);              \
            _Pragma("unroll")                           \
            for (int mi = 0; mi < 2; mi++)              \
                _Pragma("unroll")                       \
                for (int ni = 0; ni < 2; ni++) {        \
                    accg[mi][ni] = __builtin_amdgcn_mfma_f32_32x32x16_bf16(af[mi], bg[ni], accg[mi][ni], 0, 0, 0); \
                    acck[mi][ni] = __builtin_amdgcn_mfma_f32_32x32x16_bf16(af[mi], bk[ni], acck[mi][ni], 0, 0, 0); \
                }                                       \
            __builtin_amdgcn_s_setprio(0);              \
        }                                               \
        asm volatile("s_waitcnt vmcnt(" #VMC ")" ::: "memory"); \
        __builtin_amdgcn_s_barrier();                   \
    } while (0)

        STAGE_F(0, 0);
        STAGE_F(1, 32);
        asm volatile("s_waitcnt vmcnt(4)" ::: "memory");
        __builtin_amdgcn_s_barrier();

        for (int t3i = 0; t3i < 30; t3i += 3) {
            STEP_F(t3i,     0, 2, 1, 4);
            STEP_F(t3i + 1, 1, 0, 1, 4);
            STEP_F(t3i + 2, 2, 1, 1, 4);
        }
        STEP_F(30, 0, 2, 0, 0);
        STEP_F(31, 1, 0, 0, 0);
#undef STEP_F
#undef STAGE_F
    }

    // sigmoid (packed bf16 pairs) + sk2 write
    unsigned int sigp[32];
    #pragma unroll
    for (int mi = 0; mi < 2; mi++)
        #pragma unroll
        for (int ni = 0; ni < 2; ni++) {
            int n = n0 + wn * 64 + ni * 32 + l31;
            float gb = go_b[n];
            float sb_ = skip_b[n];
            #pragma unroll
            for (int reg = 0; reg < 16; reg++) {
                int row = (reg & 3) + 8 * (reg >> 2) + 4 * h;
                int t = t0 + wm * 64 + mi * 32 + row;
                float s = 1.f / (1.f + expf(-(accg[mi][ni][reg] + gb)));
                sk2[(size_t)t * OUT_DIM + n] = f2bf((acck[mi][ni][reg] + sb_) * (1.f - s));
                unsigned int pk = (unsigned int)f2bf(s);
                int idx = (mi * 2 + ni) * 8 + (reg >> 1);
                if (reg & 1) sigp[idx] |= pk << 16;
                else         sigp[idx]  = pk;
            }
        }

    // ---- mix phase, K = 2048, 64 tiles of BK=32 ----
    #pragma unroll
    for (int mi = 0; mi < 2; mi++)
        #pragma unroll
        for (int ni = 0; ni < 2; ni++)
            #pragma unroll
            for (int e = 0; e < 16; e++) accg[mi][ni][e] = 0.f;
    {
        const unsigned short* mA0 = zinb + (size_t)(t0 + r)       * KMIX + c8;
        const unsigned short* mA1 = zinb + (size_t)(t0 + 128 + r) * KMIX + c8;
        const unsigned short* mB0 = mixb + (size_t)(n0 + r)       * KMIX + c8;

#define STAGE_M(bufi, kof) do {                         \
        unsigned short* _b = &L[(bufi) * 16384];        \
        gl2lds16(mA0 + (kof), _b + dst8);               \
        gl2lds16(mA1 + (kof), _b + 4096 + dst8);        \
        gl2lds16(mB0 + (kof), _b + 8192 + dst8);        \
    } while (0)

#define STEP_M(T, CUR, NXT, DOST, VMC) do {             \
        const unsigned short* As = &L[(CUR) * 16384];   \
        const unsigned short* Bs = As + 8192;           \
        _Pragma("unroll")                               \
        for (int kh = 0; kh < 2; kh++) {                \
            const int so = ((kh * 2 + h + srot) & 3) * 8; \
            bf16x8 af[2], bf[2];                        \
            _Pragma("unroll")                           \
            for (int mi = 0; mi < 2; mi++)              \
                af[mi] = *(const bf16x8*)&As[(wm * 64 + mi * 32 + l31) * 32 + so]; \
            _Pragma("unroll")                           \
            for (int ni = 0; ni < 2; ni++)              \
                bf[ni] = *(const bf16x8*)&Bs[(wn * 64 + ni * 32 + l31) * 32 + so]; \
            if (kh == 0 && (DOST)) STAGE_M(NXT, ((T) + 2) * 32); \
            __builtin_amdgcn_s_setprio(1);              \
            _Pragma("unroll")                           \
            for (int mi = 0; mi < 2; mi++)              \
                _Pragma("unroll")                       \
                for (int ni = 0; ni < 2; ni++)          \
                    accg[mi][ni] = __builtin_amdgcn_mfma_f32_32x32x16_bf16(af[mi], bf[ni], accg[mi][ni], 0, 0, 0); \
            __builtin_amdgcn_s_setprio(0);              \
        }                                               \
        asm volatile("s_waitcnt vmcnt(" #VMC ")" ::: "memory"); \
        __builtin_amdgcn_s_barrier();                   \
    } while (0)

        STAGE_M(0, 0);
        STAGE_M(1, 32);
        asm volatile("s_waitcnt vmcnt(3)" ::: "memory");
        __builtin_amdgcn_s_barrier();

        for (int t3i = 0; t3i < 60; t3i += 3) {
            STEP_M(t3i,     0, 2, 1, 3);
            STEP_M(t3i + 1, 1, 0, 1, 3);
            STEP_M(t3i + 2, 2, 1, 1, 3);
        }
        STEP_M(60, 0, 2, 1, 3);
        STEP_M(61, 1, 0, 1, 3);
        STEP_M(62, 2, 1, 0, 0);
        STEP_M(63, 0, 2, 0, 0);
#undef STEP_M
#undef STAGE_M
    }

    #pragma unroll
    for (int mi = 0; mi < 2; mi++)
        #pragma unroll
        for (int ni = 0; ni < 2; ni++) {
            int n = n0 + wn * 64 + ni * 32 + l31;
            float mb_ = mix_b[n];
            #pragma unroll
            for (int reg = 0; reg < 16; reg++) {
                int row = (reg & 3) + 8 * (reg >> 2) + 4 * h;
                int t = t0 + wm * 64 + mi * 32 + row;
                unsigned int u = sigp[(mi * 2 + ni) * 8 + (reg >> 1)];
                float sig = bf2f((unsigned short)((reg & 1) ? (u >> 16) : (u & 0xffff)));
                zg[(size_t)t * OUT_DIM + n] = f2bf((accg[mi][ni][reg] + mb_) * sig);
            }
        }
}

// ---------------- G3: LayerNorm + residual, wave-per-row (no LDS, no barriers) ---------------
__global__ __launch_bounds__(256) void g3_ln(const unsigned short* __restrict__ zg,
        const unsigned short* __restrict__ sk2, const float* __restrict__ fstate,
        float* __restrict__ out, int out_size)
{
    const int w = threadIdx.x >> 6;
    const int lane = threadIdx.x & 63;
    const int t = blockIdx.x * 4 + w;

    const unsigned short* zr = zg  + (size_t)t * OUT_DIM + lane * 16;
    const unsigned short* sr = sk2 + (size_t)t * OUT_DIM + lane * 16;
    uint4 za = *(const uint4*)zr;
    uint4 zb = *(const uint4*)(zr + 8);
    uint4 sa = *(const uint4*)sr;
    uint4 sb2 = *(const uint4*)(sr + 8);

    float zf[16], sf[16];
    const unsigned int* zu = (const unsigned int*)&za;
    const unsigned int* su = (const unsigned int*)&sa;
    #pragma unroll
    for (int i = 0; i < 4; i++) {
        zf[2*i]   = bf2f((unsigned short)(zu[i] & 0xffff));
        zf[2*i+1] = bf2f((unsigned short)(zu[i] >> 16));
        sf[2*i]   = bf2f((unsigned short)(su[i] & 0xffff));
        sf[2*i+1] = bf2f((unsigned short)(su[i] >> 16));
    }
    const unsigned int* zu2 = (const unsigned int*)&zb;
    const unsigned int* su2 = (const unsigned int*)&sb2;
    #pragma unroll
    for (int i = 0; i < 4; i++) {
        zf[8+2*i]   = bf2f((unsigned short)(zu2[i] & 0xffff));
        zf[8+2*i+1] = bf2f((unsigned short)(zu2[i] >> 16));
        sf[8+2*i]   = bf2f((unsigned short)(su2[i] & 0xffff));
        sf[8+2*i+1] = bf2f((unsigned short)(su2[i] >> 16));
    }

    float s = 0.f, q = 0.f;
    #pragma unroll
    for (int i = 0; i < 16; i++) { s += zf[i]; q += zf[i] * zf[i]; }
    #pragma unroll
    for (int off = 32; off > 0; off >>= 1) {
        s += __shfl_down(s, off, 64);
        q += __shfl_down(q, off, 64);
    }
    s = __shfl(s, 0, 64);
    q = __shfl(q, 0, 64);
    float mu = s * (1.f / 1024.f);
    float var = q * (1.f / 1024.f) - mu * mu;
    float rs = rsqrtf(var + 1e-5f);

    float* op = out + (size_t)t * OUT_DIM + lane * 16;
    #pragma unroll
    for (int v4 = 0; v4 < 4; v4++) {
        float4 o;
        o.x = (zf[v4*4+0] - mu) * rs + sf[v4*4+0];
        o.y = (zf[v4*4+1] - mu) * rs + sf[v4*4+1];
        o.z = (zf[v4*4+2] - mu) * rs + sf[v4*4+2];
        o.w = (zf[v4*4+3] - mu) * rs + sf[v4*4+3];
        *(float4*)(op + v4 * 4) = o;
    }

    if (blockIdx.x < 8) {   // folded g4: final_state copy
        int i = blockIdx.x * 256 + threadIdx.x;
        long long base = (long long)T_DIM * OUT_DIM;
        if (base + i < (long long)out_size) out[base + i] = fstate[i];
    }
}

extern "C" void kernel_launch(void* const* d_in, const int* in_sizes, int n_in,
                              void* d_out, int out_size, void* d_ws, size_t ws_size,
                              hipStream_t stream) {
    const float* x        = (const float*)d_in[0];
    const float* state_re = (const float*)d_in[1];
    const float* state_im = (const float*)d_in[2];
    const void*  startp   = d_in[3];
    const float* pre_w    = (const float*)d_in[5];
    const float* pre_b    = (const float*)d_in[6];
    const float* gi_w     = (const float*)d_in[7];
    const float* gi_b     = (const float*)d_in[8];
    const float* go_w     = (const float*)d_in[9];
    const float* go_b     = (const float*)d_in[10];
    const float* skip_w   = (const float*)d_in[11];
    const float* skip_b   = (const float*)d_in[12];
    const float* mix_w    = (const float*)d_in[13];
    const float* mix_b    = (const float*)d_in[14];
    const float* ffa_a    = (const float*)d_in[15];
    const float* ffa_b    = (const float*)d_in[16];

    float* ws = (float*)d_ws;
    float*          gxT    = ws;
    unsigned short* zinb   = (unsigned short*)(ws + 8912896);
    unsigned short* xb     = (unsigned short*)(ws + 17301504);
    unsigned short* gob    = (unsigned short*)(ws + 21495808);
    unsigned short* skb    = (unsigned short*)(ws + 22020096);
    unsigned short* mixb   = (unsigned short*)(ws + 22544384);
    unsigned short* zg     = (unsigned short*)(ws + 23592960);
    unsigned short* sk2    = (unsigned short*)(ws + 27787264);
    float*          fstate = ws + 31981568;
    unsigned char*  mask   = (unsigned char*)(ws + 31983616);
    unsigned long long* mask64 = (unsigned long long*)(ws + 31985664);
    unsigned short* pwb    = zg;            // borrow zg region pre-gA
    unsigned short* gwb    = zg + 65536;
    float* out = (float*)d_out;

    hipLaunchKernelGGL(c0_conv,  dim3(1536), dim3(256),  0, stream, x, go_w, skip_w, mix_w, pre_w, gi_w,
                                                          startp, xb, gob, skb, mixb, pwb, gwb, mask, mask64);
    hipLaunchKernelGGL(k1_mfma,  dim3(256),  dim3(256),  0, stream, xb, pwb, gwb, pre_b, gi_b, gxT);
    hipLaunchKernelGGL(k2_scan,  dim3(256),  dim3(1024), 0, stream, gxT, mask64, state_re, state_im, ffa_a, ffa_b, zinb, fstate);
    hipLaunchKernelGGL(gA_gemm,  dim3(256),  dim3(512),  0, stream, xb, zinb, gob, skb, mixb, go_b, skip_b, mix_b, zg, sk2);
    hipLaunchKernelGGL(g3_ln,    dim3(2048), dim3(256),  0, stream, zg, sk2, fstate, out, out_size);
}